// Round 6
// baseline (1306.177 us; speedup 1.0000x reference)
//
#include <hip/hip_runtime.h>
#include <math.h>

// Sizes: B=32 S=512 V=32000 D_IN=512 D_MODEL=2048 HEADS=8 HD=64
//        N_OUT=64 N_ACT=32 M=10 MH=64 T=20

typedef __attribute__((ext_vector_type(8))) short short8v;
typedef __attribute__((ext_vector_type(4))) float f32x4;

__device__ __forceinline__ float sigf(float x) { return 1.0f / (1.0f + __expf(-x)); }
__device__ __forceinline__ float decf(float d) { return __expf(-fminf(fmaxf(d, 0.0f), 15.0f)); }
__device__ __forceinline__ unsigned short bfr(float x) {
    unsigned int u = __float_as_uint(x);
    u += 0x7FFFu + ((u >> 16) & 1u);
    return (unsigned short)(u >> 16);
}
__device__ __forceinline__ float bff(unsigned short u) {
    return __uint_as_float(((unsigned int)u) << 16);
}
__device__ __forceinline__ unsigned int bf2(float lo, float hi) {
    unsigned int ul = __float_as_uint(lo); ul += 0x7FFFu + ((ul >> 16) & 1u);
    unsigned int uh = __float_as_uint(hi); uh += 0x7FFFu + ((uh >> 16) & 1u);
    return (ul >> 16) | (uh & 0xFFFF0000u);
}
#define BLO(u) __uint_as_float((u) << 16)
#define BHI(u) __uint_as_float((u) & 0xFFFF0000u)
__device__ __forceinline__ int SWZ(int byteoff) {
    return byteoff ^ (((byteoff >> 7) & 7) << 4);
}

// ---------------------------------------------------------------------------
// K0: init trace, act (+Ab act half), aa/ba, ao/bo, stats
// ---------------------------------------------------------------------------
__global__ __launch_bounds__(256) void k0_init(
    const float* __restrict__ st_tr, const float* __restrict__ st_ac,
    const int* __restrict__ iol, const int* __restrict__ ior,
    float* __restrict__ trace, float* __restrict__ act,
    unsigned short* __restrict__ Ab,
    float* __restrict__ aaB, float* __restrict__ baB,
    float* __restrict__ aoB, float* __restrict__ boB, float* __restrict__ stats)
{
    const int i = blockIdx.x * 256 + threadIdx.x;
    if (i < 655360) {
        const int n = i & 2047;
        const int m = (i >> 11) % 10;
        trace[i] = st_tr[n * 10 + m];
    } else if (i < 720896) {
        const int j = i - 655360;
        const int n = j & 2047, b = j >> 11;
        const float v = st_ac[n];
        act[j] = v;
        Ab[b * 2560 + 512 + n] = bfr(v);
    } else if (i < 721920) {
        aaB[i - 720896] = 0.0f;
    } else if (i < 722944) {
        baB[i - 721920] = 0.0f;
    } else if (i < 724992) {
        const int j = i - 722944;
        const int k = j & 63;
        aoB[j] = st_ac[iol[k]] * st_ac[ior[k]];
    } else if (i < 727040) {
        boB[i - 724992] = 1.0f;
    } else if (i < 727104) {
        stats[i - 727040] = 0.0f;
    }
}

// ---------------------------------------------------------------------------
// S1: MFMA bf16 GEMM: C(16384x1024) = gather(emb,tok) @ WinKV^T -> khb/vhb
// grid swizzled: cb = bid>>7 so one rb's 8 c-blocks share an XCD L2
// ---------------------------------------------------------------------------
__global__ __launch_bounds__(256) void s1_kv_mfma(
    const int* __restrict__ tok, const float* __restrict__ emb,
    const float* __restrict__ Win, const float* __restrict__ b_in,
    unsigned short* __restrict__ khb, unsigned short* __restrict__ vhb)
{
    __shared__ alignas(16) unsigned short Al[128 * 64];
    __shared__ alignas(16) unsigned short Bl[128 * 64];
    const int tid = threadIdx.x;
    const int cb = blockIdx.x >> 7;
    const int rb = blockIdx.x & 127;
    const int r0 = rb * 128, c0 = cb * 128;
    int tokrow[8];
#pragma unroll
    for (int j = 0; j < 8; ++j) tokrow[j] = tok[r0 + ((tid + 256 * j) >> 4)];

    const int wid = tid >> 6, lane = tid & 63;
    const int wm = (wid >> 1) * 64, wn = (wid & 1) * 64;
    const int fr = lane & 15;
    const int fkb = (lane >> 4) * 16;
    f32x4 acc[4][4];
#pragma unroll
    for (int i = 0; i < 4; ++i)
#pragma unroll
        for (int j = 0; j < 4; ++j)
#pragma unroll
            for (int e = 0; e < 4; ++e) acc[i][j][e] = 0.0f;

    for (int kt = 0; kt < 512; kt += 64) {
        float4 av[8], bv[8];
#pragma unroll
        for (int j = 0; j < 8; ++j) {
            const int flat = tid + 256 * j;
            const int row = flat >> 4, kq4 = flat & 15;
            av[j] = *(const float4*)(emb + (size_t)tokrow[j] * 512 + kt + kq4 * 4);
            bv[j] = *(const float4*)(Win + (size_t)(512 + c0 + row) * 512 + kt + kq4 * 4);
        }
        __syncthreads();
#pragma unroll
        for (int j = 0; j < 8; ++j) {
            const int flat = tid + 256 * j;
            const int row = flat >> 4, kq4 = flat & 15;
            const int boff = row * 128 + kq4 * 8;
            uint2 pa = { bf2(av[j].x, av[j].y), bf2(av[j].z, av[j].w) };
            uint2 pb = { bf2(bv[j].x, bv[j].y), bf2(bv[j].z, bv[j].w) };
            *(uint2*)((char*)Al + SWZ(boff)) = pa;
            *(uint2*)((char*)Bl + SWZ(boff)) = pb;
        }
        __syncthreads();
#pragma unroll
        for (int ks = 0; ks < 2; ++ks) {
            short8v af[4], bfv[4];
#pragma unroll
            for (int i = 0; i < 4; ++i)
                af[i] = *(const short8v*)((const char*)Al + SWZ((wm + i * 16 + fr) * 128 + ks * 64 + fkb));
#pragma unroll
            for (int j = 0; j < 4; ++j)
                bfv[j] = *(const short8v*)((const char*)Bl + SWZ((wn + j * 16 + fr) * 128 + ks * 64 + fkb));
#pragma unroll
            for (int i = 0; i < 4; ++i)
#pragma unroll
                for (int j = 0; j < 4; ++j)
                    acc[i][j] = __builtin_amdgcn_mfma_f32_16x16x32_bf16(af[i], bfv[j], acc[i][j], 0, 0, 0);
        }
    }
    unsigned short* outbase = (c0 < 512) ? khb : vhb;
    const int ccol = (c0 < 512) ? c0 : (c0 - 512);
#pragma unroll
    for (int j = 0; j < 4; ++j) {
        const int n = wn + j * 16 + fr;
        const float bias = b_in[512 + c0 + n];
#pragma unroll
        for (int i = 0; i < 4; ++i) {
            const int mbase = wm + i * 16 + (lane >> 4) * 4;
#pragma unroll
            for (int rr = 0; rr < 4; ++rr) {
                const int gr = r0 + mbase + rr;
                outbase[(size_t)gr * 512 + ccol + n] = bfr(acc[i][j][rr] + bias);
            }
        }
    }
}

// ---------------------------------------------------------------------------
// S2: Wall[c][0..511] = bf16( Wsyn[c][0:512] @ Wattn_o )  (stride 2560)
// ---------------------------------------------------------------------------
__global__ __launch_bounds__(256) void s2_wfused(
    const float* __restrict__ Wsyn, const float* __restrict__ Wao,
    unsigned short* __restrict__ Wall)
{
    __shared__ float As[16][68];
    __shared__ float Bs[16][68];
    const int tid = threadIdx.x;
    const int cb = blockIdx.x & 7;
    const int rb = blockIdx.x >> 3;
    const int r0 = rb * 64, c0 = cb * 64;
    const int ra = tid >> 2, kq = tid & 3;
    const int bk = tid >> 4, bq = tid & 15;
    const int tx = tid & 15, ty = tid >> 4;
    float acc[4][4];
#pragma unroll
    for (int i = 0; i < 4; ++i)
#pragma unroll
        for (int j = 0; j < 4; ++j) acc[i][j] = 0.0f;

    for (int kt = 0; kt < 512; kt += 16) {
        const float4 av = *(const float4*)(Wsyn + (size_t)(r0 + ra) * 2560 + kt + kq * 4);
        const float4 bv = *(const float4*)(Wao + (size_t)(kt + bk) * 512 + c0 + bq * 4);
        __syncthreads();
        As[kq*4+0][ra] = av.x; As[kq*4+1][ra] = av.y; As[kq*4+2][ra] = av.z; As[kq*4+3][ra] = av.w;
        *(float4*)&Bs[bk][bq*4] = bv;
        __syncthreads();
#pragma unroll
        for (int kk = 0; kk < 16; ++kk) {
            const float4 a4 = *(const float4*)&As[kk][ty*4];
            const float4 b4 = *(const float4*)&Bs[kk][tx*4];
            const float a[4] = {a4.x, a4.y, a4.z, a4.w};
            const float b[4] = {b4.x, b4.y, b4.z, b4.w};
#pragma unroll
            for (int i = 0; i < 4; ++i)
#pragma unroll
                for (int j = 0; j < 4; ++j) acc[i][j] = fmaf(a[i], b[j], acc[i][j]);
        }
    }
#pragma unroll
    for (int i = 0; i < 4; ++i) {
        const int gr = r0 + ty*4 + i;
        uint2 o = { bf2(acc[i][0], acc[i][1]), bf2(acc[i][2], acc[i][3]) };
        *(uint2*)(Wall + (size_t)gr*2560 + c0 + tx*4) = o;
    }
}

// ---------------------------------------------------------------------------
// S3: bsyn2[c] = bsyn[c] + sum_k battn_o[k] * Wsyn[c][k]
// ---------------------------------------------------------------------------
__global__ __launch_bounds__(256) void s3_bias(
    const float* __restrict__ Wsyn, const float* __restrict__ battn,
    const float* __restrict__ bsyn, float* __restrict__ bsyn2)
{
    const int c = blockIdx.x * 256 + threadIdx.x;
    float s = bsyn[c];
    const float4* wr = (const float4*)(Wsyn + (size_t)c * 2560);
#pragma unroll 4
    for (int k4 = 0; k4 < 128; ++k4) {
        const float4 w = wr[k4];
        const float4 bb = *(const float4*)(battn + k4*4);
        s += w.x*bb.x + w.y*bb.y + w.z*bb.z + w.w*bb.w;
    }
    bsyn2[c] = s;
}

// ---------------------------------------------------------------------------
// S4: Wall[c][512..2559] = bf16(Wsyn[:, 512:2560])
// ---------------------------------------------------------------------------
__global__ __launch_bounds__(256) void s4_convsyn(
    const float* __restrict__ Wsyn, unsigned short* __restrict__ Wall)
{
    const int idx = blockIdx.x * 256 + threadIdx.x;
    const int row = (idx * 4) >> 11, col = (idx * 4) & 2047;
    const float4 v = *(const float4*)(Wsyn + (size_t)row * 2560 + 512 + col);
    uint2 o = { bf2(v.x, v.y), bf2(v.z, v.w) };
    *(uint2*)(Wall + (size_t)row * 2560 + 512 + col) = o;
}

// ---------------------------------------------------------------------------
// S5: NLM weight re-layout: W1t[(n>>2)*128+hh][n&3][16], W2t[(n>>2)*64+hq][n&3][2]
// ---------------------------------------------------------------------------
__global__ __launch_bounds__(256) void s5_convnlm(
    const float* __restrict__ W1, const float* __restrict__ b1,
    const float* __restrict__ W2,
    unsigned short* __restrict__ W1t, unsigned short* __restrict__ W2t)
{
    const int t = blockIdx.x * 256 + threadIdx.x;   // 0..262143
    const int n = t & 2047, hh = t >> 11;
    unsigned short tmp[16];
#pragma unroll
    for (int m = 0; m < 10; ++m) tmp[m] = bfr(W1[(size_t)(m * 128 + hh) * 2048 + n]);
    tmp[10] = bfr(b1[n * 128 + hh]);
    tmp[11] = 0; tmp[12] = 0; tmp[13] = 0; tmp[14] = 0; tmp[15] = 0;
    uint4 lo = { (unsigned)tmp[0] | ((unsigned)tmp[1] << 16), (unsigned)tmp[2] | ((unsigned)tmp[3] << 16),
                 (unsigned)tmp[4] | ((unsigned)tmp[5] << 16), (unsigned)tmp[6] | ((unsigned)tmp[7] << 16) };
    uint4 hi = { (unsigned)tmp[8] | ((unsigned)tmp[9] << 16), (unsigned)tmp[10] | ((unsigned)tmp[11] << 16),
                 (unsigned)tmp[12] | ((unsigned)tmp[13] << 16), (unsigned)tmp[14] | ((unsigned)tmp[15] << 16) };
    const size_t o1 = ((size_t)((n >> 2) * 128 + hh) * 4 + (n & 3)) * 16;
    *(uint4*)(W1t + o1) = lo;
    *(uint4*)(W1t + o1 + 8) = hi;
    if (hh < 64) {
        const unsigned short a = bfr(W2[(size_t)(hh * 2 + 0) * 2048 + n]);
        const unsigned short g = bfr(W2[(size_t)(hh * 2 + 1) * 2048 + n]);
        *(unsigned int*)(W2t + ((size_t)((n >> 2) * 64 + hh) * 4 + (n & 3)) * 2) =
            (unsigned)a | ((unsigned)g << 16);
    }
}

// ---------------------------------------------------------------------------
// S6a: M[h][d][j] = Wpq[h*64+d] . Wq[:,j] -> bf16 Mb; qc0 = bpq + Wpq.bq
// grid 64 blocks = (h, d-octet); 8 indep acc chains/thread; LDS k-combine
// ---------------------------------------------------------------------------
__global__ __launch_bounds__(256) void s6a_mproj(
    const float* __restrict__ Win, const float* __restrict__ b_in,
    const float* __restrict__ Wq, const float* __restrict__ bq,
    unsigned short* __restrict__ Mb, float* __restrict__ qc0)
{
    __shared__ float Ws[8 * 512];     // 16 KB: 8 Wpq rows
    __shared__ float bsl[512];
    __shared__ float part[8 * 264];   // [kq][dd*33 + j]
    __shared__ float partq[8 * 9];    // [kq][dd]
    const int tid = threadIdx.x;
    const int h = blockIdx.x >> 3, dq8 = blockIdx.x & 7;
    const int r0 = h * 64 + dq8 * 8;
#pragma unroll
    for (int i = 0; i < 4; ++i) {
        const int flat = tid + 256 * i;          // float4 units, 0..1023
        const int row = flat >> 7, cq = flat & 127;
        *(float4*)&Ws[row * 512 + cq * 4] =
            *(const float4*)(Win + (size_t)(r0 + row) * 512 + cq * 4);
    }
    if (tid < 128) *(float4*)&bsl[tid * 4] = *(const float4*)(bq + tid * 4);
    __syncthreads();
    const int kq = tid >> 5, j = tid & 31;
    const int k0 = kq * 64;
    float acc[8] = {0, 0, 0, 0, 0, 0, 0, 0};
    for (int k = 0; k < 64; ++k) {
        const float wqv = Wq[(k0 + k) * 32 + j];
#pragma unroll
        for (int dd = 0; dd < 8; ++dd)
            acc[dd] = fmaf(Ws[dd * 512 + k0 + k], wqv, acc[dd]);
    }
#pragma unroll
    for (int dd = 0; dd < 8; ++dd) part[kq * 264 + dd * 33 + j] = acc[dd];
    if (j < 8) {
        float s = 0.0f;
        for (int k = 0; k < 64; ++k) s = fmaf(Ws[j * 512 + k0 + k], bsl[k0 + k], s);
        partq[kq * 9 + j] = s;
    }
    __syncthreads();
    {
        const int d = tid >> 5, jj = tid & 31;
        float s = 0.0f;
#pragma unroll
        for (int q = 0; q < 8; ++q) s += part[q * 264 + d * 33 + jj];
        Mb[((size_t)(r0 + d)) * 32 + jj] = bfr(s);
    }
    if (tid < 8) {
        float s = b_in[r0 + tid];
#pragma unroll
        for (int q = 0; q < 8; ++q) s += partq[q * 9 + tid];
        qc0[r0 + tid] = s;
    }
}

// ---------------------------------------------------------------------------
// S6b: khM[b][h][s][j] = bf16( kh[r, h*64:..] . M[h][:,j] ); khc = kh . qc0
// grid 512 (32 rows each), 256 thr = (rl = tid>>3, h = tid&7)
// ---------------------------------------------------------------------------
#define MSTR 2096
__global__ __launch_bounds__(256) void s6b_khm(
    const unsigned short* __restrict__ khb, const unsigned short* __restrict__ Mb,
    const float* __restrict__ qc0,
    unsigned short* __restrict__ khM, float* __restrict__ khc)
{
    __shared__ alignas(16) unsigned short ml[8 * MSTR];
    __shared__ float ql[8 * 68];
    const int tid = threadIdx.x;
    for (int i = tid; i < 2048; i += 256) {
        const int h = i >> 8, rem = i & 255;
        *(uint4*)&ml[h * MSTR + rem * 8] = ((const uint4*)Mb)[i];
    }
    for (int i = tid; i < 512; i += 256) ql[(i >> 6) * 68 + (i & 63)] = qc0[i];
    __syncthreads();
    const int rl = tid >> 3, h = tid & 7;
    const int r = blockIdx.x * 32 + rl;
    uint4 kr[8];
#pragma unroll
    for (int i = 0; i < 8; ++i)
        kr[i] = *(const uint4*)(khb + (size_t)r * 512 + h * 64 + i * 8);
    float acc[32];
#pragma unroll
    for (int j = 0; j < 32; ++j) acc[j] = 0.0f;
    float kc = 0.0f;
    const unsigned short* mrow = &ml[h * MSTR];
    const float* qrow = &ql[h * 68];
#pragma unroll
    for (int dq = 0; dq < 8; ++dq) {
        float k8[8];
        k8[0] = BLO(kr[dq].x); k8[1] = BHI(kr[dq].x);
        k8[2] = BLO(kr[dq].y); k8[3] = BHI(kr[dq].y);
        k8[4] = BLO(kr[dq].z); k8[5] = BHI(kr[dq].z);
        k8[6] = BLO(kr[dq].w); k8[7] = BHI(kr[dq].w);
#pragma unroll
        for (int dd = 0; dd < 8; ++dd) {
            const int d = dq * 8 + dd;
            const float kf = k8[dd];
            kc = fmaf(kf, qrow[d], kc);
            const uint4 m0 = *(const uint4*)&mrow[d * 32];
            const uint4 m1 = *(const uint4*)&mrow[d * 32 + 8];
            const uint4 m2 = *(const uint4*)&mrow[d * 32 + 16];
            const uint4 m3 = *(const uint4*)&mrow[d * 32 + 24];
            acc[0]  = fmaf(kf, BLO(m0.x), acc[0]);  acc[1]  = fmaf(kf, BHI(m0.x), acc[1]);
            acc[2]  = fmaf(kf, BLO(m0.y), acc[2]);  acc[3]  = fmaf(kf, BHI(m0.y), acc[3]);
            acc[4]  = fmaf(kf, BLO(m0.z), acc[4]);  acc[5]  = fmaf(kf, BHI(m0.z), acc[5]);
            acc[6]  = fmaf(kf, BLO(m0.w), acc[6]);  acc[7]  = fmaf(kf, BHI(m0.w), acc[7]);
            acc[8]  = fmaf(kf, BLO(m1.x), acc[8]);  acc[9]  = fmaf(kf, BHI(m1.x), acc[9]);
            acc[10] = fmaf(kf, BLO(m1.y), acc[10]); acc[11] = fmaf(kf, BHI(m1.y), acc[11]);
            acc[12] = fmaf(kf, BLO(m1.z), acc[12]); acc[13] = fmaf(kf, BHI(m1.z), acc[13]);
            acc[14] = fmaf(kf, BLO(m1.w), acc[14]); acc[15] = fmaf(kf, BHI(m1.w), acc[15]);
            acc[16] = fmaf(kf, BLO(m2.x), acc[16]); acc[17] = fmaf(kf, BHI(m2.x), acc[17]);
            acc[18] = fmaf(kf, BLO(m2.y), acc[18]); acc[19] = fmaf(kf, BHI(m2.y), acc[19]);
            acc[20] = fmaf(kf, BLO(m2.z), acc[20]); acc[21] = fmaf(kf, BHI(m2.z), acc[21]);
            acc[22] = fmaf(kf, BLO(m2.w), acc[22]); acc[23] = fmaf(kf, BHI(m2.w), acc[23]);
            acc[24] = fmaf(kf, BLO(m3.x), acc[24]); acc[25] = fmaf(kf, BHI(m3.x), acc[25]);
            acc[26] = fmaf(kf, BLO(m3.y), acc[26]); acc[27] = fmaf(kf, BHI(m3.y), acc[27]);
            acc[28] = fmaf(kf, BLO(m3.z), acc[28]); acc[29] = fmaf(kf, BHI(m3.z), acc[29]);
            acc[30] = fmaf(kf, BLO(m3.w), acc[30]); acc[31] = fmaf(kf, BHI(m3.w), acc[31]);
        }
    }
    const int b = r >> 9, s = r & 511;
    unsigned short* dst = khM + (((size_t)b * 8 + h) * 512 + s) * 32;
    uint4 o0 = { bf2(acc[0],acc[1]), bf2(acc[2],acc[3]), bf2(acc[4],acc[5]), bf2(acc[6],acc[7]) };
    uint4 o1 = { bf2(acc[8],acc[9]), bf2(acc[10],acc[11]), bf2(acc[12],acc[13]), bf2(acc[14],acc[15]) };
    uint4 o2 = { bf2(acc[16],acc[17]), bf2(acc[18],acc[19]), bf2(acc[20],acc[21]), bf2(acc[22],acc[23]) };
    uint4 o3 = { bf2(acc[24],acc[25]), bf2(acc[26],acc[27]), bf2(acc[28],acc[29]), bf2(acc[30],acc[31]) };
    ((uint4*)dst)[0] = o0; ((uint4*)dst)[1] = o1; ((uint4*)dst)[2] = o2; ((uint4*)dst)[3] = o3;
    khc[((size_t)b * 8 + h) * 512 + s] = kc;
}

// ---------------------------------------------------------------------------
// K1: per (b,h), 512 thr: EMA; score = 0.125*(khM.sync + khc); shfl softmax;
// PV via early-issued coalesced vh loads -> LDS tile -> Ab bf16
// ---------------------------------------------------------------------------
__global__ __launch_bounds__(512, 1) void k1_attn(
    const float* __restrict__ act, const float* __restrict__ decay_a,
    const float* __restrict__ decay_o, const int* __restrict__ ial,
    const int* __restrict__ iar, const int* __restrict__ iol,
    const int* __restrict__ ior,
    const unsigned short* __restrict__ khM, const float* __restrict__ khc,
    const unsigned short* __restrict__ vhb, float* __restrict__ aaB,
    float* __restrict__ baB, float* __restrict__ aoB, float* __restrict__ boB,
    unsigned short* __restrict__ Ab, float* __restrict__ stats, const int u)
{
    __shared__ float sync_lds[32];
    __shared__ float sc[512];
    __shared__ float red[16];
    __shared__ float pvred[512];
    __shared__ alignas(16) unsigned short vls[512 * 72];   // 73.7 KB, pad 72
    const int tid = threadIdx.x;
    const int b = blockIdx.x >> 3, h = blockIdx.x & 7;

    // early global issues: khM row, khc, vh tile (latency hides under EMA+score)
    const size_t mb = (((size_t)b * 8 + h) * 512 + tid) * 32;
    const uint4 km0 = *(const uint4*)(khM + mb);
    const uint4 km1 = *(const uint4*)(khM + mb + 8);
    const uint4 km2 = *(const uint4*)(khM + mb + 16);
    const uint4 km3 = *(const uint4*)(khM + mb + 24);
    const float kc = khc[((size_t)b * 8 + h) * 512 + tid];
    uint4 vstg[8];
#pragma unroll
    for (int i = 0; i < 8; ++i) {
        const int flat = tid + 512 * i;
        const int row = flat >> 3, dq = flat & 7;
        vstg[i] = *(const uint4*)(vhb + (size_t)(b * 512 + row) * 512 + h * 64 + dq * 8);
    }

    if (tid < 32) {
        const int j = tid;
        const float ra = decf(decay_a[j]);
        const float pa = act[b*2048 + ial[j]] * act[b*2048 + iar[j]];
        const float aa = fmaf(ra, aaB[(u & 1)*1024 + b*32 + j], pa);
        const float ban = fmaf(ra, baB[(u & 1)*1024 + b*32 + j], 1.0f);
        if (h == 0) { aaB[((u+1)&1)*1024 + b*32 + j] = aa; baB[((u+1)&1)*1024 + b*32 + j] = ban; }
        sync_lds[j] = aa * rsqrtf(ban);
    } else if (tid >= 64 && tid < 128) {
        if (u > 0) {
            const int j = tid - 64;
            const float ro = decf(decay_o[j]);
            const float po = act[b*2048 + iol[j]] * act[b*2048 + ior[j]];
            const float ao = fmaf(ro, aoB[((u-1)&1)*2048 + b*64 + j], po);
            const float bo = fmaf(ro, boB[((u-1)&1)*2048 + b*64 + j], 1.0f);
            if (h == 0) { aoB[(u&1)*2048 + b*64 + j] = ao; boB[(u&1)*2048 + b*64 + j] = bo; }
        }
    } else if (tid >= 128 && tid < 192) {
        if (u > 0 && blockIdx.x == 0) stats[tid - 128] = 0.0f;
    }
    __syncthreads();
    // score
    float sv = kc;
    {
        const float* sy = sync_lds;
        sv = fmaf(BLO(km0.x), sy[0], sv);  sv = fmaf(BHI(km0.x), sy[1], sv);
        sv = fmaf(BLO(km0.y), sy[2], sv);  sv = fmaf(BHI(km0.y), sy[3], sv);
        sv = fmaf(BLO(km0.z), sy[4], sv);  sv = fmaf(BHI(km0.z), sy[5], sv);
        sv = fmaf(BLO(km0.w), sy[6], sv);  sv = fmaf(BHI(km0.w), sy[7], sv);
        sv = fmaf(BLO(km1.x), sy[8], sv);  sv = fmaf(BHI(km1.x), sy[9], sv);
        sv = fmaf(BLO(km1.y), sy[10], sv); sv = fmaf(BHI(km1.y), sy[11], sv);
        sv = fmaf(BLO(km1.z), sy[12], sv); sv = fmaf(BHI(km1.z), sy[13], sv);
        sv = fmaf(BLO(km1.w), sy[14], sv); sv = fmaf(BHI(km1.w), sy[15], sv);
        sv = fmaf(BLO(km2.x), sy[16], sv); sv = fmaf(BHI(km2.x), sy[17], sv);
        sv = fmaf(BLO(km2.y), sy[18], sv); sv = fmaf(BHI(km2.y), sy[19], sv);
        sv = fmaf(BLO(km2.z), sy[20], sv); sv = fmaf(BHI(km2.z), sy[21], sv);
        sv = fmaf(BLO(km2.w), sy[22], sv); sv = fmaf(BHI(km2.w), sy[23], sv);
        sv = fmaf(BLO(km3.x), sy[24], sv); sv = fmaf(BHI(km3.x), sy[25], sv);
        sv = fmaf(BLO(km3.y), sy[26], sv); sv = fmaf(BHI(km3.y), sy[27], sv);
        sv = fmaf(BLO(km3.z), sy[28], sv); sv = fmaf(BHI(km3.z), sy[29], sv);
        sv = fmaf(BLO(km3.w), sy[30], sv); sv = fmaf(BHI(km3.w), sy[31], sv);
    }
    const float v = sv * 0.125f;
    // softmax over 512
    const int wid = tid >> 6;
    float m = v;
#pragma unroll
    for (int off = 32; off > 0; off >>= 1) m = fmaxf(m, __shfl_xor(m, off));
    if ((tid & 63) == 0) red[wid] = m;
    __syncthreads();
    float mx = red[0];
#pragma unroll
    for (int j = 1; j < 8; ++j) mx = fmaxf(mx, red[j]);
    const float e = __expf(v - mx);
    sc[tid] = e;
    float s = e;
#pragma unroll
    for (int off = 32; off > 0; off >>= 1) s += __shfl_xor(s, off);
    if ((tid & 63) == 0) red[8 + wid] = s;
    __syncthreads();
    float tot = red[8];
#pragma unroll
    for (int j = 1; j < 8; ++j) tot += red[8 + j];
    const float inv = 1.0f / tot;
    // write vh tile to LDS (loads have drained by now)
#pragma unroll
    for (int i = 0; i < 8; ++i) {
        const int flat = tid + 512 * i;
        const int row = flat >> 3, dq = flat & 7;
        *(uint4*)&vls[row * 72 + dq * 8] = vstg[i];
    }
    __syncthreads();
    // PV from LDS
    {
        const int l = tid & 63, w = tid >> 6;
        float a3 = 0.0f;
#pragma unroll 8
        for (int si2 = 0; si2 < 64; ++si2) {
            const int si = w * 64 + si2;
            a3 = fmaf(sc[si], bff(vls[si * 72 + l]), a3);
        }
        pvred[w * 64 + l] = a3;
    }
    __syncthreads();
    if (tid < 64) {
        float a = 0.0f;
#pragma unroll
        for (int j = 0; j < 8; ++j) a += pvred[j*64 + tid];
        Ab[b*2560 + h*64 + tid] = bfr(a * inv);
    }
}

// ---------------------------------------------------------------------------
// K2b: synapse via MFMA: 256 blocks x 512 thr; block = 8 c-pairs; K split
// across 8 waves; LDS part-reduce; GLU -> sg; LN stats atomics
// ---------------------------------------------------------------------------
__global__ __launch_bounds__(512) void k2b_syn(
    const unsigned short* __restrict__ Ab, const unsigned short* __restrict__ Wall,
    const float* __restrict__ bsyn2, float* __restrict__ sg, float* __restrict__ stats)
{
    __shared__ float part[8 * 512];
    const int tid = threadIdx.x;
    const int c0 = blockIdx.x * 8;
    const int w = tid >> 6, lane = tid & 63, fr = lane & 15, kq = lane >> 4;
    const int col = (fr < 8) ? (c0 + fr) : (2048 + c0 + fr - 8);
    const unsigned short* wrow = Wall + (size_t)col * 2560 + w*320 + kq*8;
    const unsigned short* ar0 = Ab + (size_t)fr * 2560 + w*320 + kq*8;
    const unsigned short* ar1 = Ab + (size_t)(16 + fr) * 2560 + w*320 + kq*8;
    f32x4 acc0 = {0.f,0.f,0.f,0.f}, acc1 = {0.f,0.f,0.f,0.f};
#pragma unroll
    for (int kk = 0; kk < 10; ++kk) {
        const short8v bfrag = *(const short8v*)(wrow + kk*32);
        const short8v a0f = *(const short8v*)(ar0 + kk*32);
        const short8v a1f = *(const short8v*)(ar1 + kk*32);
        acc0 = __builtin_amdgcn_mfma_f32_16x16x32_bf16(a0f, bfrag, acc0, 0, 0, 0);
        acc1 = __builtin_amdgcn_mfma_f32_16x16x32_bf16(a1f, bfrag, acc1, 0, 0, 0);
    }
#pragma unroll
    for (int r = 0; r < 4; ++r) {
        part[w*512 + (kq*4 + r)*16 + fr] = acc0[r];
        part[w*512 + 256 + (kq*4 + r)*16 + fr] = acc1[r];
    }
    __syncthreads();
    float rs = 0.0f;
#pragma unroll
    for (int w2 = 0; w2 < 8; ++w2) rs += part[w2*512 + tid];
    const float other = __shfl_xor(rs, 8);
    const int coli = tid & 15;
    const int m = ((tid >> 8) << 4) | ((tid >> 4) & 15);
    float gval = 0.0f;
    if (coli < 8) {
        const int c = c0 + coli;
        const float va = rs + bsyn2[c];
        const float vg = other + bsyn2[2048 + c];
        gval = va * sigf(vg);
        sg[m*2048 + c] = gval;
    }
    float s1 = gval, s2v = gval*gval;
    s1 += __shfl_xor(s1, 1); s2v += __shfl_xor(s2v, 1);
    s1 += __shfl_xor(s1, 2); s2v += __shfl_xor(s2v, 2);
    s1 += __shfl_xor(s1, 4); s2v += __shfl_xor(s2v, 4);
    if (coli == 0) {
        atomicAdd(&stats[m*2],     s1);
        atomicAdd(&stats[m*2 + 1], s2v);
    }
}

// ---------------------------------------------------------------------------
// K3: LN + trace + per-neuron NLM -> act (+Ab). grid 512 (4 neurons), 256 thr
// ---------------------------------------------------------------------------
__global__ __launch_bounds__(256) void k3_nlm(
    const float* __restrict__ sg, const float* __restrict__ stats,
    const float* __restrict__ ln_g, const float* __restrict__ ln_b,
    const unsigned short* __restrict__ W1t, const unsigned short* __restrict__ W2t,
    const float* __restrict__ b2,
    float* __restrict__ trace, float* __restrict__ act,
    unsigned short* __restrict__ Ab, const int u)
{
    __shared__ float tr[128 * 12];
    __shared__ float pk[32 * 260];
    __shared__ float h2s[256];
    const int tid = threadIdx.x;
    const int n0 = blockIdx.x * 4;
    if (tid < 128) {
        const int bb = tid >> 2, nl0 = tid & 3;
        const int n = n0 + nl0;
        float* trow = &tr[tid * 12];
#pragma unroll
        for (int m = 0; m < 9; ++m) {
            const int slot = (u + 1 + m) % 10;
            trow[m] = trace[(bb*10 + slot)*2048 + n];
        }
        const float mean = stats[bb*2] * (1.0f/2048.0f);
        const float var  = stats[bb*2+1] * (1.0f/2048.0f) - mean*mean;
        const float rstd = rsqrtf(var + 1e-5f);
        const float v9 = (sg[bb*2048 + n] - mean) * rstd * ln_g[n] + ln_b[n];
        trow[9] = v9;
        trace[(bb*10 + (u % 10))*2048 + n] = v9;
    }
    const int nl = tid & 3, hg = tid >> 2;
    const int g = n0 >> 2;
    float w1a[10], w1g[10], b1a, b1g, w2v0, w2v1;
    {
        const unsigned short* pa = W1t + ((size_t)(g*128 + hg)*4 + nl)*16;
        const uint4 qa = *(const uint4*)pa;
        const uint4 qb = *(const uint4*)(pa + 8);
        w1a[0] = BLO(qa.x); w1a[1] = BHI(qa.x); w1a[2] = BLO(qa.y); w1a[3] = BHI(qa.y);
        w1a[4] = BLO(qa.z); w1a[5] = BHI(qa.z); w1a[6] = BLO(qa.w); w1a[7] = BHI(qa.w);
        w1a[8] = BLO(qb.x); w1a[9] = BHI(qb.x); b1a = BLO(qb.y);
        const unsigned short* pg = W1t + ((size_t)(g*128 + 64 + hg)*4 + nl)*16;
        const uint4 ra = *(const uint4*)pg;
        const uint4 rb = *(const uint4*)(pg + 8);
        w1g[0] = BLO(ra.x); w1g[1] = BHI(ra.x); w1g[2] = BLO(ra.y); w1g[3] = BHI(ra.y);
        w1g[4] = BLO(ra.z); w1g[5] = BHI(ra.z); w1g[6] = BLO(ra.w); w1g[7] = BHI(ra.w);
        w1g[8] = BLO(rb.x); w1g[9] = BHI(rb.x); b1g = BLO(rb.y);
        const unsigned int q2 = *(const unsigned int*)(W2t + ((size_t)(g*64 + hg)*4 + nl)*2);
        w2v0 = BLO(q2); w2v1 = BHI(q2);
    }
    __syncthreads();
    float a0[32], a1[32];
#pragma unroll
    for (int bb = 0; bb < 32; ++bb) {
        const float* trow = &tr[(bb*4 + nl)*12];
        const float4 t0 = *(const float4*)trow;
        const float4 t1 = *(const float4*)(trow + 4);
        const float2 t2 = *(const float2*)(trow + 8);
        const float t[10] = {t0.x,t0.y,t0.z,t0.w,t1.x,t1.y,t1.z,t1.w,t2.x,t2.y};
        float ha = b1a, hgv = b1g;
#pragma unroll
        for (int mm = 0; mm < 10; ++mm) {
            ha  = fmaf(t[mm], w1a[mm], ha);
            hgv = fmaf(t[mm], w1g[mm], hgv);
        }
        const float g0 = ha * sigf(hgv);
        a0[bb] = g0 * w2v0;
        a1[bb] = g0 * w2v1;
    }
    float rs = 0.0f;
#pragma unroll
    for (int pass = 0; pass < 2; ++pass) {
        __syncthreads();
        if ((hg >> 5) == pass) {
            const int hgm = hg & 31;
#pragma unroll
            for (int bb = 0; bb < 32; ++bb) {
                pk[hgm*260 + bb*8 + nl*2 + 0] = a0[bb];
                pk[hgm*260 + bb*8 + nl*2 + 1] = a1[bb];
            }
        }
        __syncthreads();
        for (int hgm = 0; hgm < 32; ++hgm) rs += pk[hgm*260 + tid];
    }
    const int onl = (tid >> 1) & 3, oo = tid & 1;
    rs += b2[(n0 + onl)*2 + oo];
    h2s[tid] = rs;
    __syncthreads();
    if (tid < 128) {
        const int bb = tid >> 2, nlx = tid & 3;
        const float h2a = h2s[tid*2], h2b = h2s[tid*2+1];
        const float actv = h2a * sigf(h2b);
        act[bb*2048 + n0 + nlx] = actv;
        Ab[bb*2560 + 512 + n0 + nlx] = bfr(actv);
    }
}

// ---------------------------------------------------------------------------
// K4: final o-update, sync_o, ratings, cert
// ---------------------------------------------------------------------------
__global__ __launch_bounds__(256) void k4_final(
    const float* __restrict__ aoB, const float* __restrict__ boB,
    const float* __restrict__ act, const float* __restrict__ decay_o,
    const int* __restrict__ iol, const int* __restrict__ ior,
    const float* __restrict__ Wout, const float* __restrict__ bout,
    float* __restrict__ out)
{
    __shared__ float sl[2048];
    const int tid = threadIdx.x;
    for (int idx = tid; idx < 2048; idx += 256) {
        const int b = idx >> 6, j = idx & 63;
        const float ro = decf(decay_o[j]);
        const float po = act[b*2048 + iol[j]] * act[b*2048 + ior[j]];
        const float ao = fmaf(ro, aoB[2048 + b*64 + j], po);
        const float bo = fmaf(ro, boB[2048 + b*64 + j], 1.0f);
        const float sv = ao * rsqrtf(bo);
        sl[idx] = sv;
        out[96 + idx] = sv;
    }
    __syncthreads();
    if (tid < 32) {
        float p = bout[0];
        for (int j = 0; j < 64; ++j) p = fmaf(sl[tid*64 + j], Wout[j], p);
        out[tid] = sigf(p);
    } else if (tid < 96) {
        out[32 + (tid - 32)] = ((tid - 32) & 1) ? 1.0f : 0.0f;
    }
}

// ---------------------------------------------------------------------------
extern "C" void kernel_launch(void* const* d_in, const int* in_sizes, int n_in,
                              void* d_out, int out_size, void* d_ws, size_t ws_size,
                              hipStream_t stream)
{
    (void)in_sizes; (void)n_in; (void)out_size;
    const int*   tok   = (const int*)  d_in[0];
    const float* emb   = (const float*)d_in[1];
    const float* st_tr = (const float*)d_in[2];
    const float* st_ac = (const float*)d_in[3];
    const float* dec_a = (const float*)d_in[4];
    const float* dec_o = (const float*)d_in[5];
    const int*   ial   = (const int*)  d_in[6];
    const int*   iar   = (const int*)  d_in[7];
    const int*   iol   = (const int*)  d_in[8];
    const int*   ior   = (const int*)  d_in[9];
    const float* Wq    = (const float*)d_in[10];
    const float* bq    = (const float*)d_in[11];
    const float* Win   = (const float*)d_in[12];
    const float* b_in  = (const float*)d_in[13];
    const float* Wao   = (const float*)d_in[14];
    const float* bao   = (const float*)d_in[15];
    const float* Wsyn  = (const float*)d_in[16];
    const float* bsyn  = (const float*)d_in[17];
    const float* ln_g  = (const float*)d_in[18];
    const float* ln_b  = (const float*)d_in[19];
    const float* W1    = (const float*)d_in[20];
    const float* b1    = (const float*)d_in[21];
    const float* W2    = (const float*)d_in[22];
    const float* b2    = (const float*)d_in[23];
    const float* Wout  = (const float*)d_in[24];
    const float* bout  = (const float*)d_in[25];
    float* out = (float*)d_out;
    char* wsb = (char*)d_ws;
    if (ws_size < (size_t)75761920) return;
    unsigned short* khb  = (unsigned short*)(wsb + 0);          // 16 MB
    unsigned short* vhb  = (unsigned short*)(wsb + 16777216);   // 16 MB
    unsigned short* Wall = (unsigned short*)(wsb + 33554432);   // 20 MB
    unsigned short* W1t  = (unsigned short*)(wsb + 54525952);   // 8 MB
    unsigned short* W2t  = (unsigned short*)(wsb + 62914560);   // 512 KB
    unsigned short* khM  = (unsigned short*)(wsb + 63438848);   // 8 MB
    float* khc  = (float*)(wsb + 71827456);                     // 512 KB
    unsigned short* Mb   = (unsigned short*)(wsb + 72351744);   // 32 KB
    float* qc0  = (float*)(wsb + 72384512);                     // 2 KB
    float* trace = (float*)(wsb + 72386560);                    // 2.5 MB
    float* actb  = (float*)(wsb + 75008000);                    // 256 KB
    float* sg    = (float*)(wsb + 75270144);                    // 256 KB
    unsigned short* Ab = (unsigned short*)(wsb + 75532288);     // 160 KB
    float* aaB   = (float*)(wsb + 75696128);
    float* baB   = (float*)(wsb + 75704320);
    float* aoB   = (float*)(wsb + 75712512);
    float* boB   = (float*)(wsb + 75728896);
    float* bs2   = (float*)(wsb + 75745280);
    float* stats = (float*)(wsb + 75761664);

    k0_init<<<dim3(2841), dim3(256), 0, stream>>>(st_tr, st_ac, iol, ior,
        trace, actb, Ab, aaB, baB, aoB, boB, stats);
    s1_kv_mfma<<<dim3(1024), dim3(256), 0, stream>>>(tok, emb, Win, b_in, khb, vhb);
    s2_wfused<<<dim3(512), dim3(256), 0, stream>>>(Wsyn, Wao, Wall);
    s3_bias<<<dim3(16), dim3(256), 0, stream>>>(Wsyn, bao, bsyn, bs2);
    s4_convsyn<<<dim3(8192), dim3(256), 0, stream>>>(Wsyn, Wall);
    s5_convnlm<<<dim3(1024), dim3(256), 0, stream>>>(W1, b1, W2, W1t, W2t);
    s6a_mproj<<<dim3(64), dim3(256), 0, stream>>>(Win, b_in, Wq, bq, Mb, qc0);
    s6b_khm<<<dim3(512), dim3(256), 0, stream>>>(khb, Mb, qc0, khM, khc);
    for (int u = 0; u < 20; ++u) {
        k1_attn<<<dim3(256), dim3(512), 0, stream>>>(actb, dec_a, dec_o,
            ial, iar, iol, ior, khM, khc, vhb,
            aaB, baB, aoB, boB, Ab, stats, u);
        k2b_syn<<<dim3(256), dim3(512), 0, stream>>>(Ab, Wall, bs2, sg, stats);
        k3_nlm<<<dim3(512), dim3(256), 0, stream>>>(sg, stats, ln_g, ln_b,
            W1t, W2t, b2, trace, actb, Ab, u);
    }
    k4_final<<<dim3(1), dim3(256), 0, stream>>>(aoB, boB, actb, dec_o,
        iol, ior, Wout, bout, out);
}

// Round 7
// 1209.528 us; speedup vs baseline: 1.0799x; 1.0799x over previous
//
#include <hip/hip_runtime.h>
#include <math.h>

// Sizes: B=32 S=512 V=32000 D_IN=512 D_MODEL=2048 HEADS=8 HD=64
//        N_OUT=64 N_ACT=32 M=10 MH=64 T=20

typedef __attribute__((ext_vector_type(8))) short short8v;
typedef __attribute__((ext_vector_type(4))) float f32x4;

__device__ __forceinline__ float sigf(float x) { return 1.0f / (1.0f + __expf(-x)); }
__device__ __forceinline__ float decf(float d) { return __expf(-fminf(fmaxf(d, 0.0f), 15.0f)); }
// single-instruction packed f32->bf16 (RNE), gfx950
__device__ __forceinline__ unsigned int bf2(float lo, float hi) {
    unsigned int r;
    asm("v_cvt_pk_bf16_f32 %0, %1, %2" : "=v"(r) : "v"(lo), "v"(hi));
    return r;
}
__device__ __forceinline__ unsigned short bfr(float x) {
    return (unsigned short)(bf2(x, 0.0f) & 0xFFFFu);
}
__device__ __forceinline__ float bff(unsigned short u) {
    return __uint_as_float(((unsigned int)u) << 16);
}
#define BLO(u) __uint_as_float((u) << 16)
#define BHI(u) __uint_as_float((u) & 0xFFFF0000u)
__device__ __forceinline__ int SWZ(int byteoff) {
    return byteoff ^ (((byteoff >> 7) & 7) << 4);
}

// ---------------------------------------------------------------------------
// K0: init trace, act (+Ab act half), aa/ba, ao/bo, stats
// ---------------------------------------------------------------------------
__global__ __launch_bounds__(256) void k0_init(
    const float* __restrict__ st_tr, const float* __restrict__ st_ac,
    const int* __restrict__ iol, const int* __restrict__ ior,
    float* __restrict__ trace, float* __restrict__ act,
    unsigned short* __restrict__ Ab,
    float* __restrict__ aaB, float* __restrict__ baB,
    float* __restrict__ aoB, float* __restrict__ boB, float* __restrict__ stats)
{
    const int i = blockIdx.x * 256 + threadIdx.x;
    if (i < 655360) {
        const int n = i & 2047;
        const int m = (i >> 11) % 10;
        trace[i] = st_tr[n * 10 + m];
    } else if (i < 720896) {
        const int j = i - 655360;
        const int n = j & 2047, b = j >> 11;
        const float v = st_ac[n];
        act[j] = v;
        Ab[b * 2560 + 512 + n] = bfr(v);
    } else if (i < 721920) {
        aaB[i - 720896] = 0.0f;
    } else if (i < 722944) {
        baB[i - 721920] = 0.0f;
    } else if (i < 724992) {
        const int j = i - 722944;
        const int k = j & 63;
        aoB[j] = st_ac[iol[k]] * st_ac[ior[k]];
    } else if (i < 727040) {
        boB[i - 724992] = 1.0f;
    } else if (i < 727104) {
        stats[i - 727040] = 0.0f;
    }
}

// ---------------------------------------------------------------------------
// S1: MFMA bf16 GEMM: C(16384x1024) = gather(emb,tok) @ WinKV^T -> khb/vhb
// grid swizzled: cb = bid>>7 so one rb's 8 c-blocks share an XCD L2
// ---------------------------------------------------------------------------
__global__ __launch_bounds__(256) void s1_kv_mfma(
    const int* __restrict__ tok, const float* __restrict__ emb,
    const float* __restrict__ Win, const float* __restrict__ b_in,
    unsigned short* __restrict__ khb, unsigned short* __restrict__ vhb)
{
    __shared__ alignas(16) unsigned short Al[128 * 64];
    __shared__ alignas(16) unsigned short Bl[128 * 64];
    const int tid = threadIdx.x;
    const int cb = blockIdx.x >> 7;
    const int rb = blockIdx.x & 127;
    const int r0 = rb * 128, c0 = cb * 128;
    int tokrow[8];
#pragma unroll
    for (int j = 0; j < 8; ++j) tokrow[j] = tok[r0 + ((tid + 256 * j) >> 4)];

    const int wid = tid >> 6, lane = tid & 63;
    const int wm = (wid >> 1) * 64, wn = (wid & 1) * 64;
    const int fr = lane & 15;
    const int fkb = (lane >> 4) * 16;
    f32x4 acc[4][4];
#pragma unroll
    for (int i = 0; i < 4; ++i)
#pragma unroll
        for (int j = 0; j < 4; ++j)
#pragma unroll
            for (int e = 0; e < 4; ++e) acc[i][j][e] = 0.0f;

    for (int kt = 0; kt < 512; kt += 64) {
        float4 av[8], bv[8];
#pragma unroll
        for (int j = 0; j < 8; ++j) {
            const int flat = tid + 256 * j;
            const int row = flat >> 4, kq4 = flat & 15;
            av[j] = *(const float4*)(emb + (size_t)tokrow[j] * 512 + kt + kq4 * 4);
            bv[j] = *(const float4*)(Win + (size_t)(512 + c0 + row) * 512 + kt + kq4 * 4);
        }
        __syncthreads();
#pragma unroll
        for (int j = 0; j < 8; ++j) {
            const int flat = tid + 256 * j;
            const int row = flat >> 4, kq4 = flat & 15;
            const int boff = row * 128 + kq4 * 8;
            uint2 pa = { bf2(av[j].x, av[j].y), bf2(av[j].z, av[j].w) };
            uint2 pb = { bf2(bv[j].x, bv[j].y), bf2(bv[j].z, bv[j].w) };
            *(uint2*)((char*)Al + SWZ(boff)) = pa;
            *(uint2*)((char*)Bl + SWZ(boff)) = pb;
        }
        __syncthreads();
#pragma unroll
        for (int ks = 0; ks < 2; ++ks) {
            short8v af[4], bfv[4];
#pragma unroll
            for (int i = 0; i < 4; ++i)
                af[i] = *(const short8v*)((const char*)Al + SWZ((wm + i * 16 + fr) * 128 + ks * 64 + fkb));
#pragma unroll
            for (int j = 0; j < 4; ++j)
                bfv[j] = *(const short8v*)((const char*)Bl + SWZ((wn + j * 16 + fr) * 128 + ks * 64 + fkb));
#pragma unroll
            for (int i = 0; i < 4; ++i)
#pragma unroll
                for (int j = 0; j < 4; ++j)
                    acc[i][j] = __builtin_amdgcn_mfma_f32_16x16x32_bf16(af[i], bfv[j], acc[i][j], 0, 0, 0);
        }
    }
    unsigned short* outbase = (c0 < 512) ? khb : vhb;
    const int ccol = (c0 < 512) ? c0 : (c0 - 512);
#pragma unroll
    for (int j = 0; j < 4; ++j) {
        const int n = wn + j * 16 + fr;
        const float bias = b_in[512 + c0 + n];
#pragma unroll
        for (int i = 0; i < 4; ++i) {
            const int mbase = wm + i * 16 + (lane >> 4) * 4;
#pragma unroll
            for (int rr = 0; rr < 4; ++rr) {
                const int gr = r0 + mbase + rr;
                outbase[(size_t)gr * 512 + ccol + n] = bfr(acc[i][j][rr] + bias);
            }
        }
    }
}

// ---------------------------------------------------------------------------
// S2: Wall[c][0..511] = bf16( Wsyn[c][0:512] @ Wattn_o )  (stride 2560)
// ---------------------------------------------------------------------------
__global__ __launch_bounds__(256) void s2_wfused(
    const float* __restrict__ Wsyn, const float* __restrict__ Wao,
    unsigned short* __restrict__ Wall)
{
    __shared__ float As[16][68];
    __shared__ float Bs[16][68];
    const int tid = threadIdx.x;
    const int cb = blockIdx.x & 7;
    const int rb = blockIdx.x >> 3;
    const int r0 = rb * 64, c0 = cb * 64;
    const int ra = tid >> 2, kq = tid & 3;
    const int bk = tid >> 4, bq = tid & 15;
    const int tx = tid & 15, ty = tid >> 4;
    float acc[4][4];
#pragma unroll
    for (int i = 0; i < 4; ++i)
#pragma unroll
        for (int j = 0; j < 4; ++j) acc[i][j] = 0.0f;

    for (int kt = 0; kt < 512; kt += 16) {
        const float4 av = *(const float4*)(Wsyn + (size_t)(r0 + ra) * 2560 + kt + kq * 4);
        const float4 bv = *(const float4*)(Wao + (size_t)(kt + bk) * 512 + c0 + bq * 4);
        __syncthreads();
        As[kq*4+0][ra] = av.x; As[kq*4+1][ra] = av.y; As[kq*4+2][ra] = av.z; As[kq*4+3][ra] = av.w;
        *(float4*)&Bs[bk][bq*4] = bv;
        __syncthreads();
#pragma unroll
        for (int kk = 0; kk < 16; ++kk) {
            const float4 a4 = *(const float4*)&As[kk][ty*4];
            const float4 b4 = *(const float4*)&Bs[kk][tx*4];
            const float a[4] = {a4.x, a4.y, a4.z, a4.w};
            const float b[4] = {b4.x, b4.y, b4.z, b4.w};
#pragma unroll
            for (int i = 0; i < 4; ++i)
#pragma unroll
                for (int j = 0; j < 4; ++j) acc[i][j] = fmaf(a[i], b[j], acc[i][j]);
        }
    }
#pragma unroll
    for (int i = 0; i < 4; ++i) {
        const int gr = r0 + ty*4 + i;
        uint2 o = { bf2(acc[i][0], acc[i][1]), bf2(acc[i][2], acc[i][3]) };
        *(uint2*)(Wall + (size_t)gr*2560 + c0 + tx*4) = o;
    }
}

// ---------------------------------------------------------------------------
// S3: bsyn2[c] = bsyn[c] + sum_k battn_o[k] * Wsyn[c][k]
// ---------------------------------------------------------------------------
__global__ __launch_bounds__(256) void s3_bias(
    const float* __restrict__ Wsyn, const float* __restrict__ battn,
    const float* __restrict__ bsyn, float* __restrict__ bsyn2)
{
    const int c = blockIdx.x * 256 + threadIdx.x;
    float s = bsyn[c];
    const float4* wr = (const float4*)(Wsyn + (size_t)c * 2560);
#pragma unroll 4
    for (int k4 = 0; k4 < 128; ++k4) {
        const float4 w = wr[k4];
        const float4 bb = *(const float4*)(battn + k4*4);
        s += w.x*bb.x + w.y*bb.y + w.z*bb.z + w.w*bb.w;
    }
    bsyn2[c] = s;
}

// ---------------------------------------------------------------------------
// S4: Wall[c][512..2559] = bf16(Wsyn[:, 512:2560])
// ---------------------------------------------------------------------------
__global__ __launch_bounds__(256) void s4_convsyn(
    const float* __restrict__ Wsyn, unsigned short* __restrict__ Wall)
{
    const int idx = blockIdx.x * 256 + threadIdx.x;
    const int row = (idx * 4) >> 11, col = (idx * 4) & 2047;
    const float4 v = *(const float4*)(Wsyn + (size_t)row * 2560 + 512 + col);
    uint2 o = { bf2(v.x, v.y), bf2(v.z, v.w) };
    *(uint2*)(Wall + (size_t)row * 2560 + 512 + col) = o;
}

// ---------------------------------------------------------------------------
// S5: NLM weight re-layout for 2-neuron k3 blocks:
//   W1t[((n>>1)*128 + hh)*2 + (n&1)][16] = {W1[m][hh][n] m=0..9, b1[n][hh], 0..}
//   W2t[((n>>1)*64 + hq)*2 + (n&1)][2]
// ---------------------------------------------------------------------------
__global__ __launch_bounds__(256) void s5_convnlm(
    const float* __restrict__ W1, const float* __restrict__ b1,
    const float* __restrict__ W2,
    unsigned short* __restrict__ W1t, unsigned short* __restrict__ W2t)
{
    const int t = blockIdx.x * 256 + threadIdx.x;   // 0..262143
    const int n = t & 2047, hh = t >> 11;
    unsigned short tmp[16];
#pragma unroll
    for (int m = 0; m < 10; ++m) tmp[m] = bfr(W1[(size_t)(m * 128 + hh) * 2048 + n]);
    tmp[10] = bfr(b1[n * 128 + hh]);
    tmp[11] = 0; tmp[12] = 0; tmp[13] = 0; tmp[14] = 0; tmp[15] = 0;
    uint4 lo = { (unsigned)tmp[0] | ((unsigned)tmp[1] << 16), (unsigned)tmp[2] | ((unsigned)tmp[3] << 16),
                 (unsigned)tmp[4] | ((unsigned)tmp[5] << 16), (unsigned)tmp[6] | ((unsigned)tmp[7] << 16) };
    uint4 hi = { (unsigned)tmp[8] | ((unsigned)tmp[9] << 16), (unsigned)tmp[10] | ((unsigned)tmp[11] << 16),
                 (unsigned)tmp[12] | ((unsigned)tmp[13] << 16), (unsigned)tmp[14] | ((unsigned)tmp[15] << 16) };
    const size_t o1 = (((size_t)(n >> 1) * 128 + hh) * 2 + (n & 1)) * 16;
    *(uint4*)(W1t + o1) = lo;
    *(uint4*)(W1t + o1 + 8) = hi;
    if (hh < 64) {
        const unsigned short a = bfr(W2[(size_t)(hh * 2 + 0) * 2048 + n]);
        const unsigned short g = bfr(W2[(size_t)(hh * 2 + 1) * 2048 + n]);
        *(unsigned int*)(W2t + (((size_t)(n >> 1) * 64 + hh) * 2 + (n & 1)) * 2) =
            (unsigned)a | ((unsigned)g << 16);
    }
}

// ---------------------------------------------------------------------------
// S6a: M[h][d][j] = Wpq[h*64+d] . Wq[:,j] -> bf16 Mb; qc0 = bpq + Wpq.bq
// grid 64 blocks = (h, d-octet); 8 indep acc chains/thread; LDS k-combine
// ---------------------------------------------------------------------------
__global__ __launch_bounds__(256) void s6a_mproj(
    const float* __restrict__ Win, const float* __restrict__ b_in,
    const float* __restrict__ Wq, const float* __restrict__ bq,
    unsigned short* __restrict__ Mb, float* __restrict__ qc0)
{
    __shared__ float Ws[8 * 512];
    __shared__ float bsl[512];
    __shared__ float part[8 * 264];
    __shared__ float partq[8 * 9];
    const int tid = threadIdx.x;
    const int h = blockIdx.x >> 3, dq8 = blockIdx.x & 7;
    const int r0 = h * 64 + dq8 * 8;
#pragma unroll
    for (int i = 0; i < 4; ++i) {
        const int flat = tid + 256 * i;
        const int row = flat >> 7, cq = flat & 127;
        *(float4*)&Ws[row * 512 + cq * 4] =
            *(const float4*)(Win + (size_t)(r0 + row) * 512 + cq * 4);
    }
    if (tid < 128) *(float4*)&bsl[tid * 4] = *(const float4*)(bq + tid * 4);
    __syncthreads();
    const int kq = tid >> 5, j = tid & 31;
    const int k0 = kq * 64;
    float acc[8] = {0, 0, 0, 0, 0, 0, 0, 0};
    for (int k = 0; k < 64; ++k) {
        const float wqv = Wq[(k0 + k) * 32 + j];
#pragma unroll
        for (int dd = 0; dd < 8; ++dd)
            acc[dd] = fmaf(Ws[dd * 512 + k0 + k], wqv, acc[dd]);
    }
#pragma unroll
    for (int dd = 0; dd < 8; ++dd) part[kq * 264 + dd * 33 + j] = acc[dd];
    if (j < 8) {
        float s = 0.0f;
        for (int k = 0; k < 64; ++k) s = fmaf(Ws[j * 512 + k0 + k], bsl[k0 + k], s);
        partq[kq * 9 + j] = s;
    }
    __syncthreads();
    {
        const int d = tid >> 5, jj = tid & 31;
        float s = 0.0f;
#pragma unroll
        for (int q = 0; q < 8; ++q) s += part[q * 264 + d * 33 + jj];
        Mb[((size_t)(r0 + d)) * 32 + jj] = bfr(s);
    }
    if (tid < 8) {
        float s = b_in[r0 + tid];
#pragma unroll
        for (int q = 0; q < 8; ++q) s += partq[q * 9 + tid];
        qc0[r0 + tid] = s;
    }
}

// ---------------------------------------------------------------------------
// S6b: khM[b][h][s][j] = bf16( kh[r, h*64:..] . M[h][:,j] ); khc = kh . qc0
// ---------------------------------------------------------------------------
#define MSTR 2096
__global__ __launch_bounds__(256) void s6b_khm(
    const unsigned short* __restrict__ khb, const unsigned short* __restrict__ Mb,
    const float* __restrict__ qc0,
    unsigned short* __restrict__ khM, float* __restrict__ khc)
{
    __shared__ alignas(16) unsigned short ml[8 * MSTR];
    __shared__ float ql[8 * 68];
    const int tid = threadIdx.x;
    for (int i = tid; i < 2048; i += 256) {
        const int h = i >> 8, rem = i & 255;
        *(uint4*)&ml[h * MSTR + rem * 8] = ((const uint4*)Mb)[i];
    }
    for (int i = tid; i < 512; i += 256) ql[(i >> 6) * 68 + (i & 63)] = qc0[i];
    __syncthreads();
    const int rl = tid >> 3, h = tid & 7;
    const int r = blockIdx.x * 32 + rl;
    uint4 kr[8];
#pragma unroll
    for (int i = 0; i < 8; ++i)
        kr[i] = *(const uint4*)(khb + (size_t)r * 512 + h * 64 + i * 8);
    float acc[32];
#pragma unroll
    for (int j = 0; j < 32; ++j) acc[j] = 0.0f;
    float kc = 0.0f;
    const unsigned short* mrow = &ml[h * MSTR];
    const float* qrow = &ql[h * 68];
#pragma unroll
    for (int dq = 0; dq < 8; ++dq) {
        float k8[8];
        k8[0] = BLO(kr[dq].x); k8[1] = BHI(kr[dq].x);
        k8[2] = BLO(kr[dq].y); k8[3] = BHI(kr[dq].y);
        k8[4] = BLO(kr[dq].z); k8[5] = BHI(kr[dq].z);
        k8[6] = BLO(kr[dq].w); k8[7] = BHI(kr[dq].w);
#pragma unroll
        for (int dd = 0; dd < 8; ++dd) {
            const int d = dq * 8 + dd;
            const float kf = k8[dd];
            kc = fmaf(kf, qrow[d], kc);
            const uint4 m0 = *(const uint4*)&mrow[d * 32];
            const uint4 m1 = *(const uint4*)&mrow[d * 32 + 8];
            const uint4 m2 = *(const uint4*)&mrow[d * 32 + 16];
            const uint4 m3 = *(const uint4*)&mrow[d * 32 + 24];
            acc[0]  = fmaf(kf, BLO(m0.x), acc[0]);  acc[1]  = fmaf(kf, BHI(m0.x), acc[1]);
            acc[2]  = fmaf(kf, BLO(m0.y), acc[2]);  acc[3]  = fmaf(kf, BHI(m0.y), acc[3]);
            acc[4]  = fmaf(kf, BLO(m0.z), acc[4]);  acc[5]  = fmaf(kf, BHI(m0.z), acc[5]);
            acc[6]  = fmaf(kf, BLO(m0.w), acc[6]);  acc[7]  = fmaf(kf, BHI(m0.w), acc[7]);
            acc[8]  = fmaf(kf, BLO(m1.x), acc[8]);  acc[9]  = fmaf(kf, BHI(m1.x), acc[9]);
            acc[10] = fmaf(kf, BLO(m1.y), acc[10]); acc[11] = fmaf(kf, BHI(m1.y), acc[11]);
            acc[12] = fmaf(kf, BLO(m1.z), acc[12]); acc[13] = fmaf(kf, BHI(m1.z), acc[13]);
            acc[14] = fmaf(kf, BLO(m1.w), acc[14]); acc[15] = fmaf(kf, BHI(m1.w), acc[15]);
            acc[16] = fmaf(kf, BLO(m2.x), acc[16]); acc[17] = fmaf(kf, BHI(m2.x), acc[17]);
            acc[18] = fmaf(kf, BLO(m2.y), acc[18]); acc[19] = fmaf(kf, BHI(m2.y), acc[19]);
            acc[20] = fmaf(kf, BLO(m2.z), acc[20]); acc[21] = fmaf(kf, BHI(m2.z), acc[21]);
            acc[22] = fmaf(kf, BLO(m2.w), acc[22]); acc[23] = fmaf(kf, BHI(m2.w), acc[23]);
            acc[24] = fmaf(kf, BLO(m3.x), acc[24]); acc[25] = fmaf(kf, BHI(m3.x), acc[25]);
            acc[26] = fmaf(kf, BLO(m3.y), acc[26]); acc[27] = fmaf(kf, BHI(m3.y), acc[27]);
            acc[28] = fmaf(kf, BLO(m3.z), acc[28]); acc[29] = fmaf(kf, BHI(m3.z), acc[29]);
            acc[30] = fmaf(kf, BLO(m3.w), acc[30]); acc[31] = fmaf(kf, BHI(m3.w), acc[31]);
        }
    }
    const int b = r >> 9, s = r & 511;
    unsigned short* dst = khM + (((size_t)b * 8 + h) * 512 + s) * 32;
    uint4 o0 = { bf2(acc[0],acc[1]), bf2(acc[2],acc[3]), bf2(acc[4],acc[5]), bf2(acc[6],acc[7]) };
    uint4 o1 = { bf2(acc[8],acc[9]), bf2(acc[10],acc[11]), bf2(acc[12],acc[13]), bf2(acc[14],acc[15]) };
    uint4 o2 = { bf2(acc[16],acc[17]), bf2(acc[18],acc[19]), bf2(acc[20],acc[21]), bf2(acc[22],acc[23]) };
    uint4 o3 = { bf2(acc[24],acc[25]), bf2(acc[26],acc[27]), bf2(acc[28],acc[29]), bf2(acc[30],acc[31]) };
    ((uint4*)dst)[0] = o0; ((uint4*)dst)[1] = o1; ((uint4*)dst)[2] = o2; ((uint4*)dst)[3] = o3;
    khc[((size_t)b * 8 + h) * 512 + s] = kc;
}

// ---------------------------------------------------------------------------
// K1: per (b,h), 512 thr: EMA; score = 0.125*(khM.sync + khc); shfl softmax;
// PV from preloaded vh regs -> Ab bf16   (round-5 measured-best version)
// ---------------------------------------------------------------------------
__global__ __launch_bounds__(512) void k1_attn(
    const float* __restrict__ act, const float* __restrict__ decay_a,
    const float* __restrict__ decay_o, const int* __restrict__ ial,
    const int* __restrict__ iar, const int* __restrict__ iol,
    const int* __restrict__ ior,
    const unsigned short* __restrict__ khM, const float* __restrict__ khc,
    const unsigned short* __restrict__ vhb, float* __restrict__ aaB,
    float* __restrict__ baB, float* __restrict__ aoB, float* __restrict__ boB,
    unsigned short* __restrict__ Ab, float* __restrict__ stats, const int u)
{
    __shared__ float sync_lds[32];
    __shared__ float sc[512];
    __shared__ float red[16];
    __shared__ float pvred[512];
    const int tid = threadIdx.x;
    const int b = blockIdx.x >> 3, h = blockIdx.x & 7;

    // early global issues (latency hides under EMA + score)
    const size_t mb = (((size_t)b * 8 + h) * 512 + tid) * 32;
    const uint4 km0 = *(const uint4*)(khM + mb);
    const uint4 km1 = *(const uint4*)(khM + mb + 8);
    const uint4 km2 = *(const uint4*)(khM + mb + 16);
    const uint4 km3 = *(const uint4*)(khM + mb + 24);
    const float kc = khc[((size_t)b * 8 + h) * 512 + tid];
    const int l = tid & 63, w = tid >> 6;
    const unsigned short* vb = vhb + ((size_t)(b * 512 + w * 64)) * 512 + h * 64 + l;
    unsigned short vraw[64];
#pragma unroll
    for (int si = 0; si < 64; ++si) vraw[si] = vb[(size_t)si * 512];

    if (tid < 32) {
        const int j = tid;
        const float ra = decf(decay_a[j]);
        const float pa = act[b*2048 + ial[j]] * act[b*2048 + iar[j]];
        const float aa = fmaf(ra, aaB[(u & 1)*1024 + b*32 + j], pa);
        const float ban = fmaf(ra, baB[(u & 1)*1024 + b*32 + j], 1.0f);
        if (h == 0) { aaB[((u+1)&1)*1024 + b*32 + j] = aa; baB[((u+1)&1)*1024 + b*32 + j] = ban; }
        sync_lds[j] = aa * rsqrtf(ban);
    } else if (tid >= 64 && tid < 128) {
        if (u > 0) {
            const int j = tid - 64;
            const float ro = decf(decay_o[j]);
            const float po = act[b*2048 + iol[j]] * act[b*2048 + ior[j]];
            const float ao = fmaf(ro, aoB[((u-1)&1)*2048 + b*64 + j], po);
            const float bo = fmaf(ro, boB[((u-1)&1)*2048 + b*64 + j], 1.0f);
            if (h == 0) { aoB[(u&1)*2048 + b*64 + j] = ao; boB[(u&1)*2048 + b*64 + j] = bo; }
        }
    } else if (tid >= 128 && tid < 192) {
        if (u > 0 && blockIdx.x == 0) stats[tid - 128] = 0.0f;
    }
    __syncthreads();
    // score
    float sv = kc;
    {
        const float* sy = sync_lds;
        sv = fmaf(BLO(km0.x), sy[0], sv);  sv = fmaf(BHI(km0.x), sy[1], sv);
        sv = fmaf(BLO(km0.y), sy[2], sv);  sv = fmaf(BHI(km0.y), sy[3], sv);
        sv = fmaf(BLO(km0.z), sy[4], sv);  sv = fmaf(BHI(km0.z), sy[5], sv);
        sv = fmaf(BLO(km0.w), sy[6], sv);  sv = fmaf(BHI(km0.w), sy[7], sv);
        sv = fmaf(BLO(km1.x), sy[8], sv);  sv = fmaf(BHI(km1.x), sy[9], sv);
        sv = fmaf(BLO(km1.y), sy[10], sv); sv = fmaf(BHI(km1.y), sy[11], sv);
        sv = fmaf(BLO(km1.z), sy[12], sv); sv = fmaf(BHI(km1.z), sy[13], sv);
        sv = fmaf(BLO(km1.w), sy[14], sv); sv = fmaf(BHI(km1.w), sy[15], sv);
        sv = fmaf(BLO(km2.x), sy[16], sv); sv = fmaf(BHI(km2.x), sy[17], sv);
        sv = fmaf(BLO(km2.y), sy[18], sv); sv = fmaf(BHI(km2.y), sy[19], sv);
        sv = fmaf(BLO(km2.z), sy[20], sv); sv = fmaf(BHI(km2.z), sy[21], sv);
        sv = fmaf(BLO(km2.w), sy[22], sv); sv = fmaf(BHI(km2.w), sy[23], sv);
        sv = fmaf(BLO(km3.x), sy[24], sv); sv = fmaf(BHI(km3.x), sy[25], sv);
        sv = fmaf(BLO(km3.y), sy[26], sv); sv = fmaf(BHI(km3.y), sy[27], sv);
        sv = fmaf(BLO(km3.z), sy[28], sv); sv = fmaf(BHI(km3.z), sy[29], sv);
        sv = fmaf(BLO(km3.w), sy[30], sv); sv = fmaf(BHI(km3.w), sy[31], sv);
    }
    const float v = sv * 0.125f;
    // softmax over 512
    const int wid = tid >> 6;
    float m = v;
#pragma unroll
    for (int off = 32; off > 0; off >>= 1) m = fmaxf(m, __shfl_xor(m, off));
    if ((tid & 63) == 0) red[wid] = m;
    __syncthreads();
    float mx = red[0];
#pragma unroll
    for (int j = 1; j < 8; ++j) mx = fmaxf(mx, red[j]);
    const float e = __expf(v - mx);
    sc[tid] = e;
    float s = e;
#pragma unroll
    for (int off = 32; off > 0; off >>= 1) s += __shfl_xor(s, off);
    if ((tid & 63) == 0) red[8 + wid] = s;
    __syncthreads();
    float tot = red[8];
#pragma unroll
    for (int j = 1; j < 8; ++j) tot += red[8 + j];
    const float inv = 1.0f / tot;
    // PV from preloaded regs
    {
        float a3 = 0.0f;
#pragma unroll
        for (int si = 0; si < 64; ++si)
            a3 = fmaf(sc[w*64 + si], bff(vraw[si]), a3);
        pvred[w*64 + l] = a3;
    }
    __syncthreads();
    if (tid < 64) {
        float a = 0.0f;
#pragma unroll
        for (int j = 0; j < 8; ++j) a += pvred[j*64 + tid];
        Ab[b*2560 + h*64 + tid] = bfr(a * inv);
    }
}

// ---------------------------------------------------------------------------
// K2b: synapse via MFMA: 256 blocks x 512 thr; block = 8 c-pairs; K split
// across 8 waves; LDS part-reduce; GLU -> sg; LN stats atomics
// ---------------------------------------------------------------------------
__global__ __launch_bounds__(512) void k2b_syn(
    const unsigned short* __restrict__ Ab, const unsigned short* __restrict__ Wall,
    const float* __restrict__ bsyn2, float* __restrict__ sg, float* __restrict__ stats)
{
    __shared__ float part[8 * 512];
    const int tid = threadIdx.x;
    const int c0 = blockIdx.x * 8;
    const int w = tid >> 6, lane = tid & 63, fr = lane & 15, kq = lane >> 4;
    const int col = (fr < 8) ? (c0 + fr) : (2048 + c0 + fr - 8);
    const unsigned short* wrow = Wall + (size_t)col * 2560 + w*320 + kq*8;
    const unsigned short* ar0 = Ab + (size_t)fr * 2560 + w*320 + kq*8;
    const unsigned short* ar1 = Ab + (size_t)(16 + fr) * 2560 + w*320 + kq*8;
    f32x4 acc0 = {0.f,0.f,0.f,0.f}, acc1 = {0.f,0.f,0.f,0.f};
#pragma unroll
    for (int kk = 0; kk < 10; ++kk) {
        const short8v bfrag = *(const short8v*)(wrow + kk*32);
        const short8v a0f = *(const short8v*)(ar0 + kk*32);
        const short8v a1f = *(const short8v*)(ar1 + kk*32);
        acc0 = __builtin_amdgcn_mfma_f32_16x16x32_bf16(a0f, bfrag, acc0, 0, 0, 0);
        acc1 = __builtin_amdgcn_mfma_f32_16x16x32_bf16(a1f, bfrag, acc1, 0, 0, 0);
    }
#pragma unroll
    for (int r = 0; r < 4; ++r) {
        part[w*512 + (kq*4 + r)*16 + fr] = acc0[r];
        part[w*512 + 256 + (kq*4 + r)*16 + fr] = acc1[r];
    }
    __syncthreads();
    float rs = 0.0f;
#pragma unroll
    for (int w2 = 0; w2 < 8; ++w2) rs += part[w2*512 + tid];
    const float other = __shfl_xor(rs, 8);
    const int coli = tid & 15;
    const int m = ((tid >> 8) << 4) | ((tid >> 4) & 15);
    float gval = 0.0f;
    if (coli < 8) {
        const int c = c0 + coli;
        const float va = rs + bsyn2[c];
        const float vg = other + bsyn2[2048 + c];
        gval = va * sigf(vg);
        sg[m*2048 + c] = gval;
    }
    float s1 = gval, s2v = gval*gval;
    s1 += __shfl_xor(s1, 1); s2v += __shfl_xor(s2v, 1);
    s1 += __shfl_xor(s1, 2); s2v += __shfl_xor(s2v, 2);
    s1 += __shfl_xor(s1, 4); s2v += __shfl_xor(s2v, 4);
    if (coli == 0) {
        atomicAdd(&stats[m*2],     s1);
        atomicAdd(&stats[m*2 + 1], s2v);
    }
}

// ---------------------------------------------------------------------------
// K3: LN + trace + per-neuron NLM -> act (+Ab).
// grid 1024 (2 neurons each), 256 thr = (nl = tid&1, hg = (tid>>1)&63, bh = tid>>7)
// single-pass LDS reduce (stride 133, <=2-way bank alias), 4 blocks/CU
// ---------------------------------------------------------------------------
__global__ __launch_bounds__(256) void k3_nlm(
    const float* __restrict__ sg, const float* __restrict__ stats,
    const float* __restrict__ ln_g, const float* __restrict__ ln_b,
    const unsigned short* __restrict__ W1t, const unsigned short* __restrict__ W2t,
    const float* __restrict__ b2,
    float* __restrict__ trace, float* __restrict__ act,
    unsigned short* __restrict__ Ab, const int u)
{
    __shared__ float tr[64 * 12];      // (bb*2+nl)*12 + m
    __shared__ float pk[64 * 133];     // hg*133 + bb*4 + nl*2 + o
    const int tid = threadIdx.x;
    const int n0 = blockIdx.x * 2;
    if (tid < 64) {
        const int bb = tid >> 1, nl0 = tid & 1;
        const int n = n0 + nl0;
        float* trow = &tr[tid * 12];
#pragma unroll
        for (int m = 0; m < 9; ++m) {
            const int slot = (u + 1 + m) % 10;
            trow[m] = trace[(bb*10 + slot)*2048 + n];
        }
        const float mean = stats[bb*2] * (1.0f/2048.0f);
        const float var  = stats[bb*2+1] * (1.0f/2048.0f) - mean*mean;
        const float rstd = rsqrtf(var + 1e-5f);
        const float v9 = (sg[bb*2048 + n] - mean) * rstd * ln_g[n] + ln_b[n];
        trow[9] = v9;
        trace[(bb*10 + (u % 10))*2048 + n] = v9;
    }
    const int nl = tid & 1, hg = (tid >> 1) & 63, bh = tid >> 7;
    float w1a[10], w1g[10], b1a, b1g, w2v0, w2v1;
    {
        const unsigned short* pa = W1t + (((size_t)blockIdx.x*128 + hg)*2 + nl)*16;
        const uint4 qa = *(const uint4*)pa;
        const uint4 qb = *(const uint4*)(pa + 8);
        w1a[0] = BLO(qa.x); w1a[1] = BHI(qa.x); w1a[2] = BLO(qa.y); w1a[3] = BHI(qa.y);
        w1a[4] = BLO(qa.z); w1a[5] = BHI(qa.z); w1a[6] = BLO(qa.w); w1a[7] = BHI(qa.w);
        w1a[8] = BLO(qb.x); w1a[9] = BHI(qb.x); b1a = BLO(qb.y);
        const unsigned short* pg = W1t + (((size_t)blockIdx.x*128 + 64 + hg)*2 + nl)*16;
        const uint4 ra = *(const uint4*)pg;
        const uint4 rb = *(const uint4*)(pg + 8);
        w1g[0] = BLO(ra.x); w1g[1] = BHI(ra.x); w1g[2] = BLO(ra.y); w1g[3] = BHI(ra.y);
        w1g[4] = BLO(ra.z); w1g[5] = BHI(ra.z); w1g[6] = BLO(ra.w); w1g[7] = BHI(ra.w);
        w1g[8] = BLO(rb.x); w1g[9] = BHI(rb.x); b1g = BLO(rb.y);
        const unsigned int q2 = *(const unsigned int*)(W2t + (((size_t)blockIdx.x*64 + hg)*2 + nl)*2);
        w2v0 = BLO(q2); w2v1 = BHI(q2);
    }
    __syncthreads();
    // compute GLU-path for 16 batches, write partials
#pragma unroll
    for (int bi = 0; bi < 16; ++bi) {
        const int bb = bh * 16 + bi;
        const float* trow = &tr[(bb*2 + nl)*12];
        const float4 t0 = *(const float4*)trow;
        const float4 t1 = *(const float4*)(trow + 4);
        const float2 t2 = *(const float2*)(trow + 8);
        const float t[10] = {t0.x,t0.y,t0.z,t0.w,t1.x,t1.y,t1.z,t1.w,t2.x,t2.y};
        float ha = b1a, hgv = b1g;
#pragma unroll
        for (int mm = 0; mm < 10; ++mm) {
            ha  = fmaf(t[mm], w1a[mm], ha);
            hgv = fmaf(t[mm], w1g[mm], hgv);
        }
        const float g0 = ha * sigf(hgv);
        pk[hg*133 + bb*4 + nl*2 + 0] = g0 * w2v0;
        pk[hg*133 + bb*4 + nl*2 + 1] = g0 * w2v1;
    }
    __syncthreads();
    // reduce over 64 hg; outputs: (bb,nl,o) = tid for tid<128
    if (tid < 128) {
        const int obb = tid >> 2, onl = (tid >> 1) & 1, oo = tid & 1;
        float rs = 0.0f;
#pragma unroll 8
        for (int q = 0; q < 64; ++q) rs += pk[q*133 + tid];
        rs += b2[(n0 + onl)*2 + oo];
        const float h2o = __shfl_xor(rs, 1);
        if (oo == 0) {
            const float actv = rs * sigf(h2o);
            act[obb*2048 + n0 + onl] = actv;
            Ab[obb*2560 + 512 + n0 + onl] = bfr(actv);
        }
    }
}

// ---------------------------------------------------------------------------
// K4: final o-update, sync_o, ratings, cert
// ---------------------------------------------------------------------------
__global__ __launch_bounds__(256) void k4_final(
    const float* __restrict__ aoB, const float* __restrict__ boB,
    const float* __restrict__ act, const float* __restrict__ decay_o,
    const int* __restrict__ iol, const int* __restrict__ ior,
    const float* __restrict__ Wout, const float* __restrict__ bout,
    float* __restrict__ out)
{
    __shared__ float sl[2048];
    const int tid = threadIdx.x;
    for (int idx = tid; idx < 2048; idx += 256) {
        const int b = idx >> 6, j = idx & 63;
        const float ro = decf(decay_o[j]);
        const float po = act[b*2048 + iol[j]] * act[b*2048 + ior[j]];
        const float ao = fmaf(ro, aoB[2048 + b*64 + j], po);
        const float bo = fmaf(ro, boB[2048 + b*64 + j], 1.0f);
        const float sv = ao * rsqrtf(bo);
        sl[idx] = sv;
        out[96 + idx] = sv;
    }
    __syncthreads();
    if (tid < 32) {
        float p = bout[0];
        for (int j = 0; j < 64; ++j) p = fmaf(sl[tid*64 + j], Wout[j], p);
        out[tid] = sigf(p);
    } else if (tid < 96) {
        out[32 + (tid - 32)] = ((tid - 32) & 1) ? 1.0f : 0.0f;
    }
}

// ---------------------------------------------------------------------------
extern "C" void kernel_launch(void* const* d_in, const int* in_sizes, int n_in,
                              void* d_out, int out_size, void* d_ws, size_t ws_size,
                              hipStream_t stream)
{
    (void)in_sizes; (void)n_in; (void)out_size;
    const int*   tok   = (const int*)  d_in[0];
    const float* emb   = (const float*)d_in[1];
    const float* st_tr = (const float*)d_in[2];
    const float* st_ac = (const float*)d_in[3];
    const float* dec_a = (const float*)d_in[4];
    const float* dec_o = (const float*)d_in[5];
    const int*   ial   = (const int*)  d_in[6];
    const int*   iar   = (const int*)  d_in[7];
    const int*   iol   = (const int*)  d_in[8];
    const int*   ior   = (const int*)  d_in[9];
    const float* Wq    = (const float*)d_in[10];
    const float* bq    = (const float*)d_in[11];
    const float* Win   = (const float*)d_in[12];
    const float* b_in  = (const float*)d_in[13];
    const float* Wao   = (const float*)d_in[14];
    const float* bao   = (const float*)d_in[15];
    const float* Wsyn  = (const float*)d_in[16];
    const float* bsyn  = (const float*)d_in[17];
    const float* ln_g  = (const float*)d_in[18];
    const float* ln_b  = (const float*)d_in[19];
    const float* W1    = (const float*)d_in[20];
    const float* b1    = (const float*)d_in[21];
    const float* W2    = (const float*)d_in[22];
    const float* b2    = (const float*)d_in[23];
    const float* Wout  = (const float*)d_in[24];
    const float* bout  = (const float*)d_in[25];
    float* out = (float*)d_out;
    char* wsb = (char*)d_ws;
    if (ws_size < (size_t)75761920) return;
    unsigned short* khb  = (unsigned short*)(wsb + 0);          // 16 MB
    unsigned short* vhb  = (unsigned short*)(wsb + 16777216);   // 16 MB
    unsigned short* Wall = (unsigned short*)(wsb + 33554432);   // 20 MB
    unsigned short* W1t  = (unsigned short*)(wsb + 54525952);   // 8 MB
    unsigned short* W2t  = (unsigned short*)(wsb + 62914560);   // 512 KB
    unsigned short* khM  = (unsigned short*)(wsb + 63438848);   // 8 MB
    float* khc  = (float*)(wsb + 71827456);                     // 512 KB
    unsigned short* Mb   = (unsigned short*)(wsb + 72351744);   // 32 KB
    float* qc0  = (float*)(wsb + 72384512);                     // 2 KB
    float* trace = (float*)(wsb + 72386560);                    // 2.5 MB
    float* actb  = (float*)(wsb + 75008000);                    // 256 KB
    float* sg    = (float*)(wsb + 75270144);                    // 256 KB
    unsigned short* Ab = (unsigned short*)(wsb + 75532288);     // 160 KB
    float* aaB   = (float*)(wsb + 75696128);
    float* baB   = (float*)(wsb + 75704320);
    float* aoB   = (float*)(wsb + 75712512);
    float* boB   = (float*)(wsb + 75728896);
    float* bs2   = (float*)(wsb + 75745280);
    float* stats = (float*)(wsb + 75761664);

    k0_init<<<dim3(2841), dim3(256), 0, stream>>>(st_tr, st_ac, iol, ior,
        trace, actb, Ab, aaB, baB, aoB, boB, stats);
    s1_kv_mfma<<<dim3(1024), dim3(256), 0, stream>>>(tok, emb, Win, b_in, khb, vhb);
    s2_wfused<<<dim3(512), dim3(256), 0, stream>>>(Wsyn, Wao, Wall);
    s3_bias<<<dim3(16), dim3(256), 0, stream>>>(Wsyn, bao, bsyn, bs2);
    s4_convsyn<<<dim3(8192), dim3(256), 0, stream>>>(Wsyn, Wall);
    s5_convnlm<<<dim3(1024), dim3(256), 0, stream>>>(W1, b1, W2, W1t, W2t);
    s6a_mproj<<<dim3(64), dim3(256), 0, stream>>>(Win, b_in, Wq, bq, Mb, qc0);
    s6b_khm<<<dim3(512), dim3(256), 0, stream>>>(khb, Mb, qc0, khM, khc);
    for (int u = 0; u < 20; ++u) {
        k1_attn<<<dim3(256), dim3(512), 0, stream>>>(actb, dec_a, dec_o,
            ial, iar, iol, ior, khM, khc, vhb,
            aaB, baB, aoB, boB, Ab, stats, u);
        k2b_syn<<<dim3(256), dim3(512), 0, stream>>>(Ab, Wall, bs2, sg, stats);
        k3_nlm<<<dim3(1024), dim3(256), 0, stream>>>(sg, stats, ln_g, ln_b,
            W1t, W2t, b2, trace, actb, Ab, u);
    }
    k4_final<<<dim3(1), dim3(256), 0, stream>>>(aoB, boB, actb, dec_o,
        iol, ior, Wout, bout, out);
}

// Round 8
// 1206.833 us; speedup vs baseline: 1.0823x; 1.0022x over previous
//
#include <hip/hip_runtime.h>
#include <math.h>

// Sizes: B=32 S=512 V=32000 D_IN=512 D_MODEL=2048 HEADS=8 HD=64
//        N_OUT=64 N_ACT=32 M=10 MH=64 T=20

typedef __attribute__((ext_vector_type(8))) short short8v;
typedef __attribute__((ext_vector_type(4))) float f32x4;

__device__ __forceinline__ float sigf(float x) { return 1.0f / (1.0f + __expf(-x)); }
__device__ __forceinline__ float decf(float d) { return __expf(-fminf(fmaxf(d, 0.0f), 15.0f)); }
// single-instruction packed f32->bf16 (RNE), gfx950
__device__ __forceinline__ unsigned int bf2(float lo, float hi) {
    unsigned int r;
    asm("v_cvt_pk_bf16_f32 %0, %1, %2" : "=v"(r) : "v"(lo), "v"(hi));
    return r;
}
__device__ __forceinline__ unsigned short bfr(float x) {
    return (unsigned short)(bf2(x, 0.0f) & 0xFFFFu);
}
__device__ __forceinline__ float bff(unsigned short u) {
    return __uint_as_float(((unsigned int)u) << 16);
}
#define BLO(u) __uint_as_float((u) << 16)
#define BHI(u) __uint_as_float((u) & 0xFFFF0000u)
__device__ __forceinline__ int SWZ(int byteoff) {
    return byteoff ^ (((byteoff >> 7) & 7) << 4);
}

// ---------------------------------------------------------------------------
// SETUP1: merged independent setup work, branch by blockIdx:
//   [0,2841)      k0: trace/act/Ab/EMA-state/stats init
//   [2841,2857)   s3: bsyn2
//   [2857,11049)  s4: Wall[:,512:2560] = bf16(Wsyn[:,512:])
//   [11049,12073) s5: NLM weight re-layout
//   [12073,12137) s6a: M = Wpq@Wq (bf16), qc0 = bpq + Wpq.bq
//   [12137,12649) s2: Wall[:,0:512] = bf16(Wsyn[:,:512] @ Wattn_o)
// ---------------------------------------------------------------------------
__global__ __launch_bounds__(256) void setup1(
    const float* __restrict__ st_tr, const float* __restrict__ st_ac,
    const int* __restrict__ iol, const int* __restrict__ ior,
    float* __restrict__ trace, float* __restrict__ act,
    unsigned short* __restrict__ Ab,
    float* __restrict__ aaB, float* __restrict__ baB,
    float* __restrict__ aoB, float* __restrict__ boB, float* __restrict__ stats,
    const float* __restrict__ Wsyn, const float* __restrict__ Wao,
    unsigned short* __restrict__ Wall,
    const float* __restrict__ battn, const float* __restrict__ bsyn,
    float* __restrict__ bsyn2,
    const float* __restrict__ W1, const float* __restrict__ b1,
    const float* __restrict__ W2,
    unsigned short* __restrict__ W1t, unsigned short* __restrict__ W2t,
    const float* __restrict__ Win, const float* __restrict__ b_in,
    const float* __restrict__ Wq, const float* __restrict__ bq,
    unsigned short* __restrict__ Mb, float* __restrict__ qc0)
{
    const int tid = threadIdx.x;
    const int bid = blockIdx.x;
    if (bid < 2841) {
        const int i = bid * 256 + tid;
        if (i < 655360) {
            const int n = i & 2047;
            const int m = (i >> 11) % 10;
            trace[i] = st_tr[n * 10 + m];
        } else if (i < 720896) {
            const int j = i - 655360;
            const int n = j & 2047, b = j >> 11;
            const float v = st_ac[n];
            act[j] = v;
            Ab[b * 2560 + 512 + n] = bfr(v);
        } else if (i < 721920) {
            aaB[i - 720896] = 0.0f;
        } else if (i < 722944) {
            baB[i - 721920] = 0.0f;
        } else if (i < 724992) {
            const int j = i - 722944;
            const int k = j & 63;
            aoB[j] = st_ac[iol[k]] * st_ac[ior[k]];
        } else if (i < 727040) {
            boB[i - 724992] = 1.0f;
        } else if (i < 727104) {
            stats[i - 727040] = 0.0f;
        }
    } else if (bid < 2857) {
        const int c = (bid - 2841) * 256 + tid;
        float s = bsyn[c];
        const float4* wr = (const float4*)(Wsyn + (size_t)c * 2560);
#pragma unroll 4
        for (int k4 = 0; k4 < 128; ++k4) {
            const float4 w = wr[k4];
            const float4 bb = *(const float4*)(battn + k4*4);
            s += w.x*bb.x + w.y*bb.y + w.z*bb.z + w.w*bb.w;
        }
        bsyn2[c] = s;
    } else if (bid < 11049) {
        const int idx = (bid - 2857) * 256 + tid;
        const int row = (idx * 4) >> 11, col = (idx * 4) & 2047;
        const float4 v = *(const float4*)(Wsyn + (size_t)row * 2560 + 512 + col);
        uint2 o = { bf2(v.x, v.y), bf2(v.z, v.w) };
        *(uint2*)(Wall + (size_t)row * 2560 + 512 + col) = o;
    } else if (bid < 12073) {
        const int t = (bid - 11049) * 256 + tid;
        const int n = t & 2047, hh = t >> 11;
        unsigned short tmp[16];
#pragma unroll
        for (int m = 0; m < 10; ++m) tmp[m] = bfr(W1[(size_t)(m * 128 + hh) * 2048 + n]);
        tmp[10] = bfr(b1[n * 128 + hh]);
        tmp[11] = 0; tmp[12] = 0; tmp[13] = 0; tmp[14] = 0; tmp[15] = 0;
        uint4 lo = { (unsigned)tmp[0] | ((unsigned)tmp[1] << 16), (unsigned)tmp[2] | ((unsigned)tmp[3] << 16),
                     (unsigned)tmp[4] | ((unsigned)tmp[5] << 16), (unsigned)tmp[6] | ((unsigned)tmp[7] << 16) };
        uint4 hi = { (unsigned)tmp[8] | ((unsigned)tmp[9] << 16), (unsigned)tmp[10] | ((unsigned)tmp[11] << 16),
                     (unsigned)tmp[12] | ((unsigned)tmp[13] << 16), (unsigned)tmp[14] | ((unsigned)tmp[15] << 16) };
        const size_t o1 = (((size_t)(n >> 1) * 128 + hh) * 2 + (n & 1)) * 16;
        *(uint4*)(W1t + o1) = lo;
        *(uint4*)(W1t + o1 + 8) = hi;
        if (hh < 64) {
            const unsigned short a = bfr(W2[(size_t)(hh * 2 + 0) * 2048 + n]);
            const unsigned short g = bfr(W2[(size_t)(hh * 2 + 1) * 2048 + n]);
            *(unsigned int*)(W2t + (((size_t)(n >> 1) * 64 + hh) * 2 + (n & 1)) * 2) =
                (unsigned)a | ((unsigned)g << 16);
        }
    } else if (bid < 12137) {
        // s6a
        __shared__ float Ws[8 * 512];
        __shared__ float bsl[512];
        __shared__ float part[8 * 264];
        __shared__ float partq[8 * 9];
        const int lb = bid - 12073;
        const int h = lb >> 3, dq8 = lb & 7;
        const int r0 = h * 64 + dq8 * 8;
#pragma unroll
        for (int i = 0; i < 4; ++i) {
            const int flat = tid + 256 * i;
            const int row = flat >> 7, cq = flat & 127;
            *(float4*)&Ws[row * 512 + cq * 4] =
                *(const float4*)(Win + (size_t)(r0 + row) * 512 + cq * 4);
        }
        if (tid < 128) *(float4*)&bsl[tid * 4] = *(const float4*)(bq + tid * 4);
        __syncthreads();
        const int kq = tid >> 5, j = tid & 31;
        const int k0 = kq * 64;
        float acc[8] = {0, 0, 0, 0, 0, 0, 0, 0};
        for (int k = 0; k < 64; ++k) {
            const float wqv = Wq[(k0 + k) * 32 + j];
#pragma unroll
            for (int dd = 0; dd < 8; ++dd)
                acc[dd] = fmaf(Ws[dd * 512 + k0 + k], wqv, acc[dd]);
        }
#pragma unroll
        for (int dd = 0; dd < 8; ++dd) part[kq * 264 + dd * 33 + j] = acc[dd];
        if (j < 8) {
            float s = 0.0f;
            for (int k = 0; k < 64; ++k) s = fmaf(Ws[j * 512 + k0 + k], bsl[k0 + k], s);
            partq[kq * 9 + j] = s;
        }
        __syncthreads();
        {
            const int d = tid >> 5, jj = tid & 31;
            float s = 0.0f;
#pragma unroll
            for (int q = 0; q < 8; ++q) s += part[q * 264 + d * 33 + jj];
            Mb[((size_t)(r0 + d)) * 32 + jj] = bfr(s);
        }
        if (tid < 8) {
            float s = b_in[r0 + tid];
#pragma unroll
            for (int q = 0; q < 8; ++q) s += partq[q * 9 + tid];
            qc0[r0 + tid] = s;
        }
    } else {
        // s2
        __shared__ float As[16][68];
        __shared__ float Bs[16][68];
        const int lb = bid - 12137;
        const int cb = lb & 7;
        const int rb = lb >> 3;
        const int r0 = rb * 64, c0 = cb * 64;
        const int ra = tid >> 2, kq = tid & 3;
        const int bk = tid >> 4, bq2 = tid & 15;
        const int tx = tid & 15, ty = tid >> 4;
        float acc[4][4];
#pragma unroll
        for (int i = 0; i < 4; ++i)
#pragma unroll
            for (int j = 0; j < 4; ++j) acc[i][j] = 0.0f;

        for (int kt = 0; kt < 512; kt += 16) {
            const float4 av = *(const float4*)(Wsyn + (size_t)(r0 + ra) * 2560 + kt + kq * 4);
            const float4 bv = *(const float4*)(Wao + (size_t)(kt + bk) * 512 + c0 + bq2 * 4);
            __syncthreads();
            As[kq*4+0][ra] = av.x; As[kq*4+1][ra] = av.y; As[kq*4+2][ra] = av.z; As[kq*4+3][ra] = av.w;
            *(float4*)&Bs[bk][bq2*4] = bv;
            __syncthreads();
#pragma unroll
            for (int kk = 0; kk < 16; ++kk) {
                const float4 a4 = *(const float4*)&As[kk][ty*4];
                const float4 b4 = *(const float4*)&Bs[kk][tx*4];
                const float a[4] = {a4.x, a4.y, a4.z, a4.w};
                const float b[4] = {b4.x, b4.y, b4.z, b4.w};
#pragma unroll
                for (int i = 0; i < 4; ++i)
#pragma unroll
                    for (int j = 0; j < 4; ++j) acc[i][j] = fmaf(a[i], b[j], acc[i][j]);
            }
        }
#pragma unroll
        for (int i = 0; i < 4; ++i) {
            const int gr = r0 + ty*4 + i;
            uint2 o = { bf2(acc[i][0], acc[i][1]), bf2(acc[i][2], acc[i][3]) };
            *(uint2*)(Wall + (size_t)gr*2560 + c0 + tx*4) = o;
        }
    }
}

// ---------------------------------------------------------------------------
// S1: MFMA bf16 GEMM: C(16384x1024) = gather(emb,tok) @ WinKV^T -> khb/vhb
// LDS-transposed epilogue: coalesced 256B row stores (kills write amplification)
// ---------------------------------------------------------------------------
__global__ __launch_bounds__(256) void s1_kv_mfma(
    const int* __restrict__ tok, const float* __restrict__ emb,
    const float* __restrict__ Win, const float* __restrict__ b_in,
    unsigned short* __restrict__ khb, unsigned short* __restrict__ vhb)
{
    __shared__ alignas(16) unsigned short SM[17408];   // Al(8192) + Bl(8192); epi: [128][136]
    unsigned short* Al = SM;
    unsigned short* Bl = SM + 8192;
    const int tid = threadIdx.x;
    const int cb = blockIdx.x >> 7;
    const int rb = blockIdx.x & 127;
    const int r0 = rb * 128, c0 = cb * 128;
    int tokrow[8];
#pragma unroll
    for (int j = 0; j < 8; ++j) tokrow[j] = tok[r0 + ((tid + 256 * j) >> 4)];

    const int wid = tid >> 6, lane = tid & 63;
    const int wm = (wid >> 1) * 64, wn = (wid & 1) * 64;
    const int fr = lane & 15;
    const int fkb = (lane >> 4) * 16;
    f32x4 acc[4][4];
#pragma unroll
    for (int i = 0; i < 4; ++i)
#pragma unroll
        for (int j = 0; j < 4; ++j)
#pragma unroll
            for (int e = 0; e < 4; ++e) acc[i][j][e] = 0.0f;

    for (int kt = 0; kt < 512; kt += 64) {
        float4 av[8], bv[8];
#pragma unroll
        for (int j = 0; j < 8; ++j) {
            const int flat = tid + 256 * j;
            const int row = flat >> 4, kq4 = flat & 15;
            av[j] = *(const float4*)(emb + (size_t)tokrow[j] * 512 + kt + kq4 * 4);
            bv[j] = *(const float4*)(Win + (size_t)(512 + c0 + row) * 512 + kt + kq4 * 4);
        }
        __syncthreads();
#pragma unroll
        for (int j = 0; j < 8; ++j) {
            const int flat = tid + 256 * j;
            const int row = flat >> 4, kq4 = flat & 15;
            const int boff = row * 128 + kq4 * 8;
            uint2 pa = { bf2(av[j].x, av[j].y), bf2(av[j].z, av[j].w) };
            uint2 pb = { bf2(bv[j].x, bv[j].y), bf2(bv[j].z, bv[j].w) };
            *(uint2*)((char*)Al + SWZ(boff)) = pa;
            *(uint2*)((char*)Bl + SWZ(boff)) = pb;
        }
        __syncthreads();
#pragma unroll
        for (int ks = 0; ks < 2; ++ks) {
            short8v af[4], bfv[4];
#pragma unroll
            for (int i = 0; i < 4; ++i)
                af[i] = *(const short8v*)((const char*)Al + SWZ((wm + i * 16 + fr) * 128 + ks * 64 + fkb));
#pragma unroll
            for (int j = 0; j < 4; ++j)
                bfv[j] = *(const short8v*)((const char*)Bl + SWZ((wn + j * 16 + fr) * 128 + ks * 64 + fkb));
#pragma unroll
            for (int i = 0; i < 4; ++i)
#pragma unroll
                for (int j = 0; j < 4; ++j)
                    acc[i][j] = __builtin_amdgcn_mfma_f32_16x16x32_bf16(af[i], bfv[j], acc[i][j], 0, 0, 0);
        }
    }
    // epilogue: frags -> LDS [128][136] bf16 -> coalesced row stores
    __syncthreads();
#pragma unroll
    for (int j = 0; j < 4; ++j) {
        const int n = wn + j * 16 + fr;
        const float bias = b_in[512 + c0 + n];
#pragma unroll
        for (int i = 0; i < 4; ++i) {
            const int rbase = wm + i * 16 + (lane >> 4) * 4;
#pragma unroll
            for (int rr = 0; rr < 4; ++rr)
                SM[(rbase + rr) * 136 + n] = bfr(acc[i][j][rr] + bias);
        }
    }
    __syncthreads();
    unsigned short* outbase = (c0 < 512) ? khb : vhb;
    const int ccol = (c0 < 512) ? c0 : (c0 - 512);
    {
        const int orow = tid >> 1, oh = tid & 1;
        unsigned short* gdst = outbase + (size_t)(r0 + orow) * 512 + ccol + oh * 64;
        const unsigned short* lsrc = SM + orow * 136 + oh * 64;
#pragma unroll
        for (int q = 0; q < 8; ++q)
            *(uint4*)(gdst + q * 8) = *(const uint4*)(lsrc + q * 8);
    }
}

// ---------------------------------------------------------------------------
// SETUP2 (after s1): branch by blockIdx:
//   [0,32)   s6w: WMt[h*32+j][c] = sum_d Wpk[h*64+d][c]*M[h][d][j]; kmc = bpk.M
//   [32,544) s6c: khc[b,h,s] = kh[r,h*64:].qc0[h*64:]   (identical math to old)
// ---------------------------------------------------------------------------
__global__ __launch_bounds__(256) void setup2(
    const float* __restrict__ Win, const float* __restrict__ b_in,
    const unsigned short* __restrict__ Mb, const float* __restrict__ qc0,
    const unsigned short* __restrict__ khb,
    unsigned short* __restrict__ WMt, float* __restrict__ kmc,
    float* __restrict__ khc)
{
    const int tid = threadIdx.x;
    const int bid = blockIdx.x;
    if (bid < 32) {
        __shared__ float Ws[64 * 128];
        __shared__ float Mf[64 * 33];
        __shared__ float bp[64];
        const int h = bid >> 2, ct = bid & 3;
#pragma unroll
        for (int i = 0; i < 8; ++i) {
            const int flat4 = tid + 256 * i;        // 2048 float4 = 64x128 f32
            const int d = flat4 >> 5, cl4 = flat4 & 31;
            *(float4*)&Ws[d * 128 + cl4 * 4] =
                *(const float4*)(Win + (size_t)(512 + h * 64 + d) * 512 + ct * 128 + cl4 * 4);
        }
#pragma unroll
        for (int i = 0; i < 8; ++i) {
            const int flat = tid + 256 * i;          // 2048 = 64x32
            const int d = flat >> 5, j2 = flat & 31;
            Mf[d * 33 + j2] = bff(Mb[(size_t)(h * 64 + d) * 32 + j2]);
        }
        if (tid < 64) bp[tid] = b_in[512 + h * 64 + tid];
        __syncthreads();
        const int j = tid & 31, clg = tid >> 5;
        float accw[16];
#pragma unroll
        for (int i = 0; i < 16; ++i) accw[i] = 0.0f;
        for (int d = 0; d < 64; ++d) {
            const float mf = Mf[d * 33 + j];
            const float* wr = &Ws[d * 128 + clg * 16];
#pragma unroll
            for (int i = 0; i < 16; ++i) accw[i] = fmaf(wr[i], mf, accw[i]);
        }
#pragma unroll
        for (int i = 0; i < 16; ++i)
            WMt[(size_t)(h * 32 + j) * 512 + ct * 128 + clg * 16 + i] = bfr(accw[i]);
        if (ct == 0 && clg == 0) {
            float s = 0.0f;
            for (int d = 0; d < 64; ++d) s = fmaf(bp[d], Mf[d * 33 + j], s);
            kmc[h * 32 + j] = s;
        }
    } else {
        __shared__ float qls[512];
        const int sb = bid - 32;
        qls[tid] = qc0[tid];
        qls[tid + 256] = qc0[tid + 256];
        __syncthreads();
        const int h = tid & 7, rl = tid >> 3;
        const int r = sb * 32 + rl;
        const unsigned short* kr = khb + (size_t)r * 512 + h * 64;
        const float* q8 = &qls[h * 64];
        float kc = 0.0f;
#pragma unroll
        for (int i = 0; i < 8; ++i) {
            const uint4 kv = *(const uint4*)(kr + i * 8);
            kc = fmaf(BLO(kv.x), q8[i*8+0], kc); kc = fmaf(BHI(kv.x), q8[i*8+1], kc);
            kc = fmaf(BLO(kv.y), q8[i*8+2], kc); kc = fmaf(BHI(kv.y), q8[i*8+3], kc);
            kc = fmaf(BLO(kv.z), q8[i*8+4], kc); kc = fmaf(BHI(kv.z), q8[i*8+5], kc);
            kc = fmaf(BLO(kv.w), q8[i*8+6], kc); kc = fmaf(BHI(kv.w), q8[i*8+7], kc);
        }
        khc[((size_t)(r >> 9) * 8 + h) * 512 + (r & 511)] = kc;
    }
}

// ---------------------------------------------------------------------------
// S7: MFMA bf16 GEMM: khM(16384 x 256) = gather(emb,tok) @ WMt^T + kmc
// (same structure as s1, N=256; replaces the scalar s6b at ~4x fewer cycles)
// ---------------------------------------------------------------------------
__global__ __launch_bounds__(256) void s7_khm_mfma(
    const int* __restrict__ tok, const float* __restrict__ emb,
    const unsigned short* __restrict__ WMt, const float* __restrict__ kmc,
    unsigned short* __restrict__ khM)
{
    __shared__ alignas(16) unsigned short Al[128 * 64];
    __shared__ alignas(16) unsigned short Bl[128 * 64];
    const int tid = threadIdx.x;
    const int cb = blockIdx.x >> 7;
    const int rb = blockIdx.x & 127;
    const int r0 = rb * 128, c0 = cb * 128;
    int tokrow[8];
#pragma unroll
    for (int j = 0; j < 8; ++j) tokrow[j] = tok[r0 + ((tid + 256 * j) >> 4)];

    const int wid = tid >> 6, lane = tid & 63;
    const int wm = (wid >> 1) * 64, wn = (wid & 1) * 64;
    const int fr = lane & 15;
    const int fkb = (lane >> 4) * 16;
    f32x4 acc[4][4];
#pragma unroll
    for (int i = 0; i < 4; ++i)
#pragma unroll
        for (int j = 0; j < 4; ++j)
#pragma unroll
            for (int e = 0; e < 4; ++e) acc[i][j][e] = 0.0f;

    for (int kt = 0; kt < 512; kt += 64) {
        float4 av[8];
        uint4 bv4[4];
#pragma unroll
        for (int j = 0; j < 8; ++j) {
            const int flat = tid + 256 * j;
            const int row = flat >> 4, kq4 = flat & 15;
            av[j] = *(const float4*)(emb + (size_t)tokrow[j] * 512 + kt + kq4 * 4);
        }
#pragma unroll
        for (int j = 0; j < 4; ++j) {
            const int flat = tid + 256 * j;
            const int row = flat >> 3, kq8 = flat & 7;
            bv4[j] = *(const uint4*)(WMt + (size_t)(c0 + row) * 512 + kt + kq8 * 8);
        }
        __syncthreads();
#pragma unroll
        for (int j = 0; j < 8; ++j) {
            const int flat = tid + 256 * j;
            const int row = flat >> 4, kq4 = flat & 15;
            const int boff = row * 128 + kq4 * 8;
            uint2 pa = { bf2(av[j].x, av[j].y), bf2(av[j].z, av[j].w) };
            *(uint2*)((char*)Al + SWZ(boff)) = pa;
        }
#pragma unroll
        for (int j = 0; j < 4; ++j) {
            const int flat = tid + 256 * j;
            const int row = flat >> 3, kq8 = flat & 7;
            const int boff = row * 128 + kq8 * 16;
            *(uint4*)((char*)Bl + SWZ(boff)) = bv4[j];
        }
        __syncthreads();
#pragma unroll
        for (int ks = 0; ks < 2; ++ks) {
            short8v af[4], bfv[4];
#pragma unroll
            for (int i = 0; i < 4; ++i)
                af[i] = *(const short8v*)((const char*)Al + SWZ((wm + i * 16 + fr) * 128 + ks * 64 + fkb));
#pragma unroll
            for (int j = 0; j < 4; ++j)
                bfv[j] = *(const short8v*)((const char*)Bl + SWZ((wn + j * 16 + fr) * 128 + ks * 64 + fkb));
#pragma unroll
            for (int i = 0; i < 4; ++i)
#pragma unroll
                for (int j = 0; j < 4; ++j)
                    acc[i][j] = __builtin_amdgcn_mfma_f32_16x16x32_bf16(af[i], bfv[j], acc[i][j], 0, 0, 0);
        }
    }
#pragma unroll
    for (int j = 0; j < 4; ++j) {
        const int n = wn + j * 16 + fr;
        const int gc = c0 + n;
        const int h = gc >> 5, jj = gc & 31;
        const float kadd = kmc[gc];
#pragma unroll
        for (int i = 0; i < 4; ++i) {
            const int rbase = wm + i * 16 + (lane >> 4) * 4;
#pragma unroll
            for (int rr = 0; rr < 4; ++rr) {
                const int gr = r0 + rbase + rr;
                khM[(((size_t)(gr >> 9) * 8 + h) * 512 + (gr & 511)) * 32 + jj] =
                    bfr(acc[i][j][rr] + kadd);
            }
        }
    }
}

// ---------------------------------------------------------------------------
// K1: per (b,h), 512 thr: EMA; score = 0.125*(khM.sync + khc); shfl softmax;
// PV from preloaded vh regs -> Ab bf16
// ---------------------------------------------------------------------------
__global__ __launch_bounds__(512) void k1_attn(
    const float* __restrict__ act, const float* __restrict__ decay_a,
    const float* __restrict__ decay_o, const int* __restrict__ ial,
    const int* __restrict__ iar, const int* __restrict__ iol,
    const int* __restrict__ ior,
    const unsigned short* __restrict__ khM, const float* __restrict__ khc,
    const unsigned short* __restrict__ vhb, float* __restrict__ aaB,
    float* __restrict__ baB, float* __restrict__ aoB, float* __restrict__ boB,
    unsigned short* __restrict__ Ab, float* __restrict__ stats, const int u)
{
    __shared__ float sync_lds[32];
    __shared__ float sc[512];
    __shared__ float red[16];
    __shared__ float pvred[512];
    const int tid = threadIdx.x;
    const int b = blockIdx.x >> 3, h = blockIdx.x & 7;

    const size_t mb = (((size_t)b * 8 + h) * 512 + tid) * 32;
    const uint4 km0 = *(const uint4*)(khM + mb);
    const uint4 km1 = *(const uint4*)(khM + mb + 8);
    const uint4 km2 = *(const uint4*)(khM + mb + 16);
    const uint4 km3 = *(const uint4*)(khM + mb + 24);
    const float kc = khc[((size_t)b * 8 + h) * 512 + tid];
    const int l = tid & 63, w = tid >> 6;
    const unsigned short* vb = vhb + ((size_t)(b * 512 + w * 64)) * 512 + h * 64 + l;
    unsigned short vraw[64];
#pragma unroll
    for (int si = 0; si < 64; ++si) vraw[si] = vb[(size_t)si * 512];

    if (tid < 32) {
        const int j = tid;
        const float ra = decf(decay_a[j]);
        const float pa = act[b*2048 + ial[j]] * act[b*2048 + iar[j]];
        const float aa = fmaf(ra, aaB[(u & 1)*1024 + b*32 + j], pa);
        const float ban = fmaf(ra, baB[(u & 1)*1024 + b*32 + j], 1.0f);
        if (h == 0) { aaB[((u+1)&1)*1024 + b*32 + j] = aa; baB[((u+1)&1)*1024 + b*32 + j] = ban; }
        sync_lds[j] = aa * rsqrtf(ban);
    } else if (tid >= 64 && tid < 128) {
        if (u > 0) {
            const int j = tid - 64;
            const float ro = decf(decay_o[j]);
            const float po = act[b*2048 + iol[j]] * act[b*2048 + ior[j]];
            const float ao = fmaf(ro, aoB[((u-1)&1)*2048 + b*64 + j], po);
            const float bo = fmaf(ro, boB[((u-1)&1)*2048 + b*64 + j], 1.0f);
            if (h == 0) { aoB[(u&1)*2048 + b*64 + j] = ao; boB[(u&1)*2048 + b*64 + j] = bo; }
        }
    } else if (tid >= 128 && tid < 192) {
        if (u > 0 && blockIdx.x == 0) stats[tid - 128] = 0.0f;
    }
    __syncthreads();
    float sv = kc;
    {
        const float* sy = sync_lds;
        sv = fmaf(BLO(km0.x), sy[0], sv);  sv = fmaf(BHI(km0.x), sy[1], sv);
        sv = fmaf(BLO(km0.y), sy[2], sv);  sv = fmaf(BHI(km0.y), sy[3], sv);
        sv = fmaf(BLO(km0.z), sy[4], sv);  sv = fmaf(BHI(km0.z), sy[5], sv);
        sv = fmaf(BLO(km0.w), sy[6], sv);  sv = fmaf(BHI(km0.w), sy[7], sv);
        sv = fmaf(BLO(km1.x), sy[8], sv);  sv = fmaf(BHI(km1.x), sy[9], sv);
        sv = fmaf(BLO(km1.y), sy[10], sv); sv = fmaf(BHI(km1.y), sy[11], sv);
        sv = fmaf(BLO(km1.z), sy[12], sv); sv = fmaf(BHI(km1.z), sy[13], sv);
        sv = fmaf(BLO(km1.w), sy[14], sv); sv = fmaf(BHI(km1.w), sy[15], sv);
        sv = fmaf(BLO(km2.x), sy[16], sv); sv = fmaf(BHI(km2.x), sy[17], sv);
        sv = fmaf(BLO(km2.y), sy[18], sv); sv = fmaf(BHI(km2.y), sy[19], sv);
        sv = fmaf(BLO(km2.z), sy[20], sv); sv = fmaf(BHI(km2.z), sy[21], sv);
        sv = fmaf(BLO(km2.w), sy[22], sv); sv = fmaf(BHI(km2.w), sy[23], sv);
        sv = fmaf(BLO(km3.x), sy[24], sv); sv = fmaf(BHI(km3.x), sy[25], sv);
        sv = fmaf(BLO(km3.y), sy[26], sv); sv = fmaf(BHI(km3.y), sy[27], sv);
        sv = fmaf(BLO(km3.z), sy[28], sv); sv = fmaf(BHI(km3.z), sy[29], sv);
        sv = fmaf(BLO(km3.w), sy[30], sv); sv = fmaf(BHI(km3.w), sy[31], sv);
    }
    const float v = sv * 0.125f;
    const int wid = tid >> 6;
    float m = v;
#pragma unroll
    for (int off = 32; off > 0; off >>= 1) m = fmaxf(m, __shfl_xor(m, off));
    if ((tid & 63) == 0) red[wid] = m;
    __syncthreads();
    float mx = red[0];
#pragma unroll
    for (int j = 1; j < 8; ++j) mx = fmaxf(mx, red[j]);
    const float e = __expf(v - mx);
    sc[tid] = e;
    float s = e;
#pragma unroll
    for (int off = 32; off > 0; off >>= 1) s += __shfl_xor(s, off);
    if ((tid & 63) == 0) red[8 + wid] = s;
    __syncthreads();
    float tot = red[8];
#pragma unroll
    for (int j = 1; j < 8; ++j) tot += red[8 + j];
    const float inv = 1.0f / tot;
    {
        float a3 = 0.0f;
#pragma unroll
        for (int si = 0; si < 64; ++si)
            a3 = fmaf(sc[w*64 + si], bff(vraw[si]), a3);
        pvred[w*64 + l] = a3;
    }
    __syncthreads();
    if (tid < 64) {
        float a = 0.0f;
#pragma unroll
        for (int j = 0; j < 8; ++j) a += pvred[j*64 + tid];
        Ab[b*2560 + h*64 + tid] = bfr(a * inv);
    }
}

// ---------------------------------------------------------------------------
// K2b: synapse via MFMA -> GLU -> sg; LN stats atomics
// ---------------------------------------------------------------------------
__global__ __launch_bounds__(512) void k2b_syn(
    const unsigned short* __restrict__ Ab, const unsigned short* __restrict__ Wall,
    const float* __restrict__ bsyn2, float* __restrict__ sg, float* __restrict__ stats)
{
    __shared__ float part[8 * 512];
    const int tid = threadIdx.x;
    const int c0 = blockIdx.x * 8;
    const int w = tid >> 6, lane = tid & 63, fr = lane & 15, kq = lane >> 4;
    const int col = (fr < 8) ? (c0 + fr) : (2048 + c0 + fr - 8);
    const unsigned short* wrow = Wall + (size_t)col * 2560 + w*320 + kq*8;
    const unsigned short* ar0 = Ab + (size_t)fr * 2560 + w*320 + kq*8;
    const unsigned short* ar1 = Ab + (size_t)(16 + fr) * 2560 + w*320 + kq*8;
    f32x4 acc0 = {0.f,0.f,0.f,0.f}, acc1 = {0.f,0.f,0.f,0.f};
#pragma unroll
    for (int kk = 0; kk < 10; ++kk) {
        const short8v bfrag = *(const short8v*)(wrow + kk*32);
        const short8v a0f = *(const short8v*)(ar0 + kk*32);
        const short8v a1f = *(const short8v*)(ar1 + kk*32);
        acc0 = __builtin_amdgcn_mfma_f32_16x16x32_bf16(a0f, bfrag, acc0, 0, 0, 0);
        acc1 = __builtin_amdgcn_mfma_f32_16x16x32_bf16(a1f, bfrag, acc1, 0, 0, 0);
    }
#pragma unroll
    for (int r = 0; r < 4; ++r) {
        part[w*512 + (kq*4 + r)*16 + fr] = acc0[r];
        part[w*512 + 256 + (kq*4 + r)*16 + fr] = acc1[r];
    }
    __syncthreads();
    float rs = 0.0f;
#pragma unroll
    for (int w2 = 0; w2 < 8; ++w2) rs += part[w2*512 + tid];
    const float other = __shfl_xor(rs, 8);
    const int coli = tid & 15;
    const int m = ((tid >> 8) << 4) | ((tid >> 4) & 15);
    float gval = 0.0f;
    if (coli < 8) {
        const int c = c0 + coli;
        const float va = rs + bsyn2[c];
        const float vg = other + bsyn2[2048 + c];
        gval = va * sigf(vg);
        sg[m*2048 + c] = gval;
    }
    float s1 = gval, s2v = gval*gval;
    s1 += __shfl_xor(s1, 1); s2v += __shfl_xor(s2v, 1);
    s1 += __shfl_xor(s1, 2); s2v += __shfl_xor(s2v, 2);
    s1 += __shfl_xor(s1, 4); s2v += __shfl_xor(s2v, 4);
    if (coli == 0) {
        atomicAdd(&stats[m*2],     s1);
        atomicAdd(&stats[m*2 + 1], s2v);
    }
}

// ---------------------------------------------------------------------------
// K3: LN + trace + per-neuron NLM -> act (+Ab). grid 1024 (2 neurons), 256 thr
// ---------------------------------------------------------------------------
__global__ __launch_bounds__(256) void k3_nlm(
    const float* __restrict__ sg, const float* __restrict__ stats,
    const float* __restrict__ ln_g, const float* __restrict__ ln_b,
    const unsigned short* __restrict__ W1t, const unsigned short* __restrict__ W2t,
    const float* __restrict__ b2,
    float* __restrict__ trace, float* __restrict__ act,
    unsigned short* __restrict__ Ab, const int u)
{
    __shared__ float tr[64 * 12];
    __shared__ float pk[64 * 133];
    const int tid = threadIdx.x;
    const int n0 = blockIdx.x * 2;
    if (tid < 64) {
        const int bb = tid >> 1, nl0 = tid & 1;
        const int n = n0 + nl0;
        float* trow = &tr[tid * 12];
#pragma unroll
        for (int m = 0; m < 9; ++m) {
            const int slot = (u + 1 + m) % 10;
            trow[m] = trace[(bb*10 + slot)*2048 + n];
        }
        const float mean = stats[bb*2] * (1.0f/2048.0f);
        const float var  = stats[bb*2+1] * (1.0f/2048.0f) - mean*mean;
        const float rstd = rsqrtf(var + 1e-5f);
        const float v9 = (sg[bb*2048 + n] - mean) * rstd * ln_g[n] + ln_b[n];
        trow[9] = v9;
        trace[(bb*10 + (u % 10))*2048 + n] = v9;
    }
    const int nl = tid & 1, hg = (tid >> 1) & 63, bh = tid >> 7;
    float w1a[10], w1g[10], b1a, b1g, w2v0, w2v1;
    {
        const unsigned short* pa = W1t + (((size_t)blockIdx.x*128 + hg)*2 + nl)*16;
        const uint4 qa = *(const uint4*)pa;
        const uint4 qb = *(const uint4*)(pa + 8);
        w1a[0] = BLO(qa.x); w1a[1] = BHI(qa.x); w1a[2] = BLO(qa.y); w1a[3] = BHI(qa.y);
        w1a[4] = BLO(qa.z); w1a[5] = BHI(qa.z); w1a[6] = BLO(qa.w); w1a[7] = BHI(qa.w);
        w1a[8] = BLO(qb.x); w1a[9] = BHI(qb.x); b1a = BLO(qb.y);
        const unsigned short* pg = W1t + (((size_t)blockIdx.x*128 + 64 + hg)*2 + nl)*16;
        const uint4 ra = *(const uint4*)pg;
        const uint4 rb = *(const uint4*)(pg + 8);
        w1g[0] = BLO(ra.x); w1g[1] = BHI(ra.x); w1g[2] = BLO(ra.y); w1g[3] = BHI(ra.y);
        w1g[4] = BLO(ra.z); w1g[5] = BHI(ra.z); w1g[6] = BLO(ra.w); w1g[7] = BHI(ra.w);
        w1g[8] = BLO(rb.x); w1g[9] = BHI(rb.x); b1g = BLO(rb.y);
        const unsigned int q2 = *(const unsigned int*)(W2t + (((size_t)blockIdx.x*64 + hg)*2 + nl)*2);
        w2v0 = BLO(q2); w2v1 = BHI(q2);
    }
    __syncthreads();
#pragma unroll
    for (int bi = 0; bi < 16; ++bi) {
        const int bb = bh * 16 + bi;
        const float* trow = &tr[(bb*2 + nl)*12];
        const float4 t0 = *(const float4*)trow;
        const float4 t1 = *(const float4*)(trow + 4);
        const float2 t2 = *(const float2*)(trow + 8);
        const float t[10] = {t0.x,t0.y,t0.z,t0.w,t1.x,t1.y,t1.z,t1.w,t2.x,t2.y};
        float ha = b1a, hgv = b1g;
#pragma unroll
        for (int mm = 0; mm < 10; ++mm) {
            ha  = fmaf(t[mm], w1a[mm], ha);
            hgv = fmaf(t[mm], w1g[mm], hgv);
        }
        const float g0 = ha * sigf(hgv);
        pk[hg*133 + bb*4 + nl*2 + 0] = g0 * w2v0;
        pk[hg*133 + bb*4 + nl*2 + 1] = g0 * w2v1;
    }
    __syncthreads();
    if (tid < 128) {
        const int obb = tid >> 2, onl = (tid >> 1) & 1, oo = tid & 1;
        float rs = 0.0f;
#pragma unroll 8
        for (int q = 0; q < 64; ++q) rs += pk[q*133 + tid];
        rs += b2[(n0 + onl)*2 + oo];
        const float h2o = __shfl_xor(rs, 1);
        if (oo == 0) {
            const float actv = rs * sigf(h2o);
            act[obb*2048 + n0 + onl] = actv;
            Ab[obb*2560 + 512 + n0 + onl] = bfr(actv);
        }
    }
}

// ---------------------------------------------------------------------------
// K4: final o-update, sync_o, ratings, cert
// ---------------------------------------------------------------------------
__global__ __launch_bounds__(256) void k4_final(
    const float* __restrict__ aoB, const float* __restrict__ boB,
    const float* __restrict__ act, const float* __restrict__ decay_o,
    const int* __restrict__ iol, const int* __restrict__ ior,
    const float* __restrict__ Wout, const float* __restrict__ bout,
    float* __restrict__ out)
{
    __shared__ float sl[2048];
    const int tid = threadIdx.x;
    for (int idx = tid; idx < 2048; idx += 256) {
        const int b = idx >> 6, j = idx & 63;
        const float ro = decf(decay_o[j]);
        const float po = act[b*2048 + iol[j]] * act[b*2048 + ior[j]];
        const float ao = fmaf(ro, aoB[2048 + b*64 + j], po);
        const float bo = fmaf(ro, boB[2048 + b*64 + j], 1.0f);
        const float sv = ao * rsqrtf(bo);
        sl[idx] = sv;
        out[96 + idx] = sv;
    }
    __syncthreads();
    if (tid < 32) {
        float p = bout[0];
        for (int j = 0; j < 64; ++j) p = fmaf(sl[tid*64 + j], Wout[j], p);
        out[tid] = sigf(p);
    } else if (tid < 96) {
        out[32 + (tid - 32)] = ((tid - 32) & 1) ? 1.0f : 0.0f;
    }
}

// ---------------------------------------------------------------------------
extern "C" void kernel_launch(void* const* d_in, const int* in_sizes, int n_in,
                              void* d_out, int out_size, void* d_ws, size_t ws_size,
                              hipStream_t stream)
{
    (void)in_sizes; (void)n_in; (void)out_size;
    const int*   tok   = (const int*)  d_in[0];
    const float* emb   = (const float*)d_in[1];
    const float* st_tr = (const float*)d_in[2];
    const float* st_ac = (const float*)d_in[3];
    const float* dec_a = (const float*)d_in[4];
    const float* dec_o = (const float*)d_in[5];
    const int*   ial   = (const int*)  d_in[6];
    const int*   iar   = (const int*)  d_in[7];
    const int*   iol   = (const int*)  d_in[8];
    const int*   ior   = (const int*)  d_in[9];
    const float* Wq    = (const float*)d_in[10];
    const float* bq    = (const float*)d_in[11];
    const float* Win   = (const float*)d_in[12];
    const float* b_in  = (const float*)d_in[13];
    const float* Wao   = (const float*)d_in[14];
    const float* bao   = (const float*)d_in[15];
    const float* Wsyn  = (const float*)d_in[16];
    const float* bsyn  = (const float*)d_in[17];
    const float* ln_g  = (const float*)d_in[18];
    const float* ln_b  = (const float*)d_in[19];
    const float* W1    = (const float*)d_in[20];
    const float* b1    = (const float*)d_in[21];
    const float* W2    = (const float*)d_in[22];
    const float* b2    = (const float*)d_in[23];
    const float* Wout  = (const float*)d_in[24];
    const float* bout  = (const float*)d_in[25];
    float* out = (float*)d_out;
    char* wsb = (char*)d_ws;
    if (ws_size < (size_t)76025088) return;
    unsigned short* khb  = (unsigned short*)(wsb + 0);          // 16 MB
    unsigned short* vhb  = (unsigned short*)(wsb + 16777216);   // 16 MB
    unsigned short* Wall = (unsigned short*)(wsb + 33554432);   // 20 MB
    unsigned short* W1t  = (unsigned short*)(wsb + 54525952);   // 8 MB
    unsigned short* W2t  = (unsigned short*)(wsb + 62914560);   // 512 KB
    unsigned short* khM  = (unsigned short*)(wsb + 63438848);   // 8 MB
    float* khc  = (float*)(wsb + 71827456);                     // 512 KB
    unsigned short* Mb   = (unsigned short*)(wsb + 72351744);   // 32 KB
    float* qc0  = (float*)(wsb + 72384512);                     // 2 KB
    float* trace = (float*)(wsb + 72386560);                    // 2.5 MB
    float* actb  = (float*)(wsb + 75008000);                    // 256 KB
    float* sg    = (float*)(wsb + 75270144);                    // 256 KB
    unsigned short* Ab = (unsigned short*)(wsb + 75532288);     // 160 KB
    float* aaB   = (float*)(wsb + 75696128);
    float* baB   = (float*)(wsb + 75704320);
    float* aoB   = (float*)(wsb + 75712512);
    float* boB   = (float*)(wsb + 75728896);
    float* bs2   = (float*)(wsb + 75745280);
    float* stats = (float*)(wsb + 75761664);
    unsigned short* WMt = (unsigned short*)(wsb + 75761920);    // 256 KB (256x512 bf16)
    float* kmc  = (float*)(wsb + 76024064);                     // 1 KB

    setup1<<<dim3(12649), dim3(256), 0, stream>>>(
        st_tr, st_ac, iol, ior, trace, actb, Ab, aaB, baB, aoB, boB, stats,
        Wsyn, Wao, Wall, bao, bsyn, bs2, W1, b1, W2, W1t, W2t,
        Win, b_in, Wq, bq, Mb, qc0);
    s1_kv_mfma<<<dim3(1024), dim3(256), 0, stream>>>(tok, emb, Win, b_in, khb, vhb);
    setup2<<<dim3(544), dim3(256), 0, stream>>>(Win, b_in, Mb, qc0, khb, WMt, kmc, khc);
    s7_khm_mfma<<<dim3(256), dim3(256), 0, stream>>>(tok, emb, WMt, kmc, khM);
    for (int u = 0; u < 20; ++u) {
        k1_attn<<<dim3(256), dim3(512), 0, stream>>>(actb, dec_a, dec_o,
            ial, iar, iol, ior, khM, khc, vhb,
            aaB, baB, aoB, boB, Ab, stats, u);
        k2b_syn<<<dim3(256), dim3(512), 0, stream>>>(Ab, Wall, bs2, sg, stats);
        k3_nlm<<<dim3(1024), dim3(256), 0, stream>>>(sg, stats, ln_g, ln_b,
            W1t, W2t, b2, trace, actb, Ab, u);
    }
    k4_final<<<dim3(1), dim3(256), 0, stream>>>(aoB, boB, actb, dec_o,
        iol, ior, Wout, bout, out);
}

// Round 9
// 1187.363 us; speedup vs baseline: 1.1001x; 1.0164x over previous
//
#include <hip/hip_runtime.h>
#include <math.h>

// Sizes: B=32 S=512 V=32000 D_IN=512 D_MODEL=2048 HEADS=8 HD=64
//        N_OUT=64 N_ACT=32 M=10 MH=64 T=20

typedef __attribute__((ext_vector_type(8))) short short8v;
typedef __attribute__((ext_vector_type(4))) float f32x4;

__device__ __forceinline__ float sigf(float x) { return 1.0f / (1.0f + __expf(-x)); }
__device__ __forceinline__ float decf(float d) { return __expf(-fminf(fmaxf(d, 0.0f), 15.0f)); }
// single-instruction packed f32->bf16 (RNE), gfx950
__device__ __forceinline__ unsigned int bf2(float lo, float hi) {
    unsigned int r;
    asm("v_cvt_pk_bf16_f32 %0, %1, %2" : "=v"(r) : "v"(lo), "v"(hi));
    return r;
}
__device__ __forceinline__ unsigned short bfr(float x) {
    return (unsigned short)(bf2(x, 0.0f) & 0xFFFFu);
}
__device__ __forceinline__ float bff(unsigned short u) {
    return __uint_as_float(((unsigned int)u) << 16);
}
#define BLO(u) __uint_as_float((u) << 16)
#define BHI(u) __uint_as_float((u) & 0xFFFF0000u)
__device__ __forceinline__ int SWZ(int byteoff) {
    return byteoff ^ (((byteoff >> 7) & 7) << 4);
}
// Wallt layout: [cg 0..255][kb 0..319][fr 0..15][ke 0..7]
//   col c (0..4095): cg=(c&2047)>>3, fr=(c&7)+(c<2048?0:8); k: kb=k>>3, ke=k&7
__device__ __forceinline__ size_t wallt_idx(int c, int k) {
    const int cg = (c & 2047) >> 3;
    const int fr = (c & 7) + ((c < 2048) ? 0 : 8);
    return (((size_t)cg * 320 + (k >> 3)) * 16 + fr) * 8 + (k & 7);
}

// ---------------------------------------------------------------------------
// SETUP1: merged cheap setup work (uniform cost per block), branch by blockIdx:
//   [0,2841)      k0: trace/act/Ab/EMA-state/stats init
//   [2841,2857)   s3: bsyn2
//   [2857,11049)  s4: Wallt[k>=512] = bf16(Wsyn[:,512:])
//   [11049,12073) s5: NLM weight re-layout
//   [12073,12137) s6a: M = Wpq@Wq (bf16), qc0 = bpq + Wpq.bq
// ---------------------------------------------------------------------------
__global__ __launch_bounds__(256) void setup1(
    const float* __restrict__ st_tr, const float* __restrict__ st_ac,
    const int* __restrict__ iol, const int* __restrict__ ior,
    float* __restrict__ trace, float* __restrict__ act,
    unsigned short* __restrict__ Ab,
    float* __restrict__ aaB, float* __restrict__ baB,
    float* __restrict__ aoB, float* __restrict__ boB, float* __restrict__ stats,
    const float* __restrict__ Wsyn, unsigned short* __restrict__ Wallt,
    const float* __restrict__ battn, const float* __restrict__ bsyn,
    float* __restrict__ bsyn2,
    const float* __restrict__ W1, const float* __restrict__ b1,
    const float* __restrict__ W2,
    unsigned short* __restrict__ W1t, unsigned short* __restrict__ W2t,
    const float* __restrict__ Win, const float* __restrict__ b_in,
    const float* __restrict__ Wq, const float* __restrict__ bq,
    unsigned short* __restrict__ Mb, float* __restrict__ qc0)
{
    const int tid = threadIdx.x;
    const int bid = blockIdx.x;
    if (bid < 2841) {
        const int i = bid * 256 + tid;
        if (i < 655360) {
            const int n = i & 2047;
            const int m = (i >> 11) % 10;
            trace[i] = st_tr[n * 10 + m];
        } else if (i < 720896) {
            const int j = i - 655360;
            const int n = j & 2047, b = j >> 11;
            const float v = st_ac[n];
            act[j] = v;
            Ab[b * 2560 + 512 + n] = bfr(v);
        } else if (i < 721920) {
            aaB[i - 720896] = 0.0f;
        } else if (i < 722944) {
            baB[i - 721920] = 0.0f;
        } else if (i < 724992) {
            const int j = i - 722944;
            const int k = j & 63;
            aoB[j] = st_ac[iol[k]] * st_ac[ior[k]];
        } else if (i < 727040) {
            boB[i - 724992] = 1.0f;
        } else if (i < 727104) {
            stats[i - 727040] = 0.0f;
        }
    } else if (bid < 2857) {
        const int c = (bid - 2841) * 256 + tid;
        float s = bsyn[c];
        const float4* wr = (const float4*)(Wsyn + (size_t)c * 2560);
#pragma unroll 4
        for (int k4 = 0; k4 < 128; ++k4) {
            const float4 w = wr[k4];
            const float4 bb = *(const float4*)(battn + k4*4);
            s += w.x*bb.x + w.y*bb.y + w.z*bb.z + w.w*bb.w;
        }
        bsyn2[c] = s;
    } else if (bid < 11049) {
        const int idx = (bid - 2857) * 256 + tid;
        const int row = (idx * 4) >> 11, col = (idx * 4) & 2047;
        const float4 v = *(const float4*)(Wsyn + (size_t)row * 2560 + 512 + col);
        uint2 o = { bf2(v.x, v.y), bf2(v.z, v.w) };
        *(uint2*)(Wallt + wallt_idx(row, 512 + col)) = o;
    } else if (bid < 12073) {
        const int t = (bid - 11049) * 256 + tid;
        const int n = t & 2047, hh = t >> 11;
        unsigned short tmp[16];
#pragma unroll
        for (int m = 0; m < 10; ++m) tmp[m] = bfr(W1[(size_t)(m * 128 + hh) * 2048 + n]);
        tmp[10] = bfr(b1[n * 128 + hh]);
        tmp[11] = 0; tmp[12] = 0; tmp[13] = 0; tmp[14] = 0; tmp[15] = 0;
        uint4 lo = { (unsigned)tmp[0] | ((unsigned)tmp[1] << 16), (unsigned)tmp[2] | ((unsigned)tmp[3] << 16),
                     (unsigned)tmp[4] | ((unsigned)tmp[5] << 16), (unsigned)tmp[6] | ((unsigned)tmp[7] << 16) };
        uint4 hi = { (unsigned)tmp[8] | ((unsigned)tmp[9] << 16), (unsigned)tmp[10] | ((unsigned)tmp[11] << 16),
                     (unsigned)tmp[12] | ((unsigned)tmp[13] << 16), (unsigned)tmp[14] | ((unsigned)tmp[15] << 16) };
        const size_t o1 = (((size_t)(n >> 1) * 128 + hh) * 2 + (n & 1)) * 16;
        *(uint4*)(W1t + o1) = lo;
        *(uint4*)(W1t + o1 + 8) = hi;
        if (hh < 64) {
            const unsigned short a = bfr(W2[(size_t)(hh * 2 + 0) * 2048 + n]);
            const unsigned short g = bfr(W2[(size_t)(hh * 2 + 1) * 2048 + n]);
            *(unsigned int*)(W2t + (((size_t)(n >> 1) * 64 + hh) * 2 + (n & 1)) * 2) =
                (unsigned)a | ((unsigned)g << 16);
        }
    } else {
        // s6a
        __shared__ float Ws[8 * 512];
        __shared__ float bsl[512];
        __shared__ float part[8 * 264];
        __shared__ float partq[8 * 9];
        const int lb = bid - 12073;
        const int h = lb >> 3, dq8 = lb & 7;
        const int r0 = h * 64 + dq8 * 8;
#pragma unroll
        for (int i = 0; i < 4; ++i) {
            const int flat = tid + 256 * i;
            const int row = flat >> 7, cq = flat & 127;
            *(float4*)&Ws[row * 512 + cq * 4] =
                *(const float4*)(Win + (size_t)(r0 + row) * 512 + cq * 4);
        }
        if (tid < 128) *(float4*)&bsl[tid * 4] = *(const float4*)(bq + tid * 4);
        __syncthreads();
        const int kq = tid >> 5, j = tid & 31;
        const int k0 = kq * 64;
        float acc[8] = {0, 0, 0, 0, 0, 0, 0, 0};
        for (int k = 0; k < 64; ++k) {
            const float wqv = Wq[(k0 + k) * 32 + j];
#pragma unroll
            for (int dd = 0; dd < 8; ++dd)
                acc[dd] = fmaf(Ws[dd * 512 + k0 + k], wqv, acc[dd]);
        }
#pragma unroll
        for (int dd = 0; dd < 8; ++dd) part[kq * 264 + dd * 33 + j] = acc[dd];
        if (j < 8) {
            float s = 0.0f;
            for (int k = 0; k < 64; ++k) s = fmaf(Ws[j * 512 + k0 + k], bsl[k0 + k], s);
            partq[kq * 9 + j] = s;
        }
        __syncthreads();
        {
            const int d = tid >> 5, jj = tid & 31;
            float s = 0.0f;
#pragma unroll
            for (int q = 0; q < 8; ++q) s += part[q * 264 + d * 33 + jj];
            Mb[((size_t)(r0 + d)) * 32 + jj] = bfr(s);
        }
        if (tid < 8) {
            float s = b_in[r0 + tid];
#pragma unroll
            for (int q = 0; q < 8; ++q) s += partq[q * 9 + tid];
            qc0[r0 + tid] = s;
        }
    }
}

// ---------------------------------------------------------------------------
// S2: Wallt[k<512] = bf16( Wsyn[:, :512] @ Wattn_o )   (64x64 tiles, 512 blocks)
// ---------------------------------------------------------------------------
__global__ __launch_bounds__(256) void s2_wfused(
    const float* __restrict__ Wsyn, const float* __restrict__ Wao,
    unsigned short* __restrict__ Wallt)
{
    __shared__ float As[16][68];
    __shared__ float Bs[16][68];
    const int tid = threadIdx.x;
    const int cb = blockIdx.x & 7;
    const int rb = blockIdx.x >> 3;
    const int r0 = rb * 64, c0 = cb * 64;
    const int ra = tid >> 2, kq = tid & 3;
    const int bk = tid >> 4, bq2 = tid & 15;
    const int tx = tid & 15, ty = tid >> 4;
    float acc[4][4];
#pragma unroll
    for (int i = 0; i < 4; ++i)
#pragma unroll
        for (int j = 0; j < 4; ++j) acc[i][j] = 0.0f;

    for (int kt = 0; kt < 512; kt += 16) {
        const float4 av = *(const float4*)(Wsyn + (size_t)(r0 + ra) * 2560 + kt + kq * 4);
        const float4 bv = *(const float4*)(Wao + (size_t)(kt + bk) * 512 + c0 + bq2 * 4);
        __syncthreads();
        As[kq*4+0][ra] = av.x; As[kq*4+1][ra] = av.y; As[kq*4+2][ra] = av.z; As[kq*4+3][ra] = av.w;
        *(float4*)&Bs[bk][bq2*4] = bv;
        __syncthreads();
#pragma unroll
        for (int kk = 0; kk < 16; ++kk) {
            const float4 a4 = *(const float4*)&As[kk][ty*4];
            const float4 b4 = *(const float4*)&Bs[kk][tx*4];
            const float a[4] = {a4.x, a4.y, a4.z, a4.w};
            const float b[4] = {b4.x, b4.y, b4.z, b4.w};
#pragma unroll
            for (int i = 0; i < 4; ++i)
#pragma unroll
                for (int j = 0; j < 4; ++j) acc[i][j] = fmaf(a[i], b[j], acc[i][j]);
        }
    }
#pragma unroll
    for (int i = 0; i < 4; ++i) {
        const int gr = r0 + ty*4 + i;
        uint2 o = { bf2(acc[i][0], acc[i][1]), bf2(acc[i][2], acc[i][3]) };
        *(uint2*)(Wallt + wallt_idx(gr, c0 + tx*4)) = o;
    }
}

// ---------------------------------------------------------------------------
// S1: MFMA bf16 GEMM: C(16384x1024) = gather(emb,tok) @ WinKV^T -> khb/vhb
// LDS-transposed epilogue: coalesced 256B row stores
// ---------------------------------------------------------------------------
__global__ __launch_bounds__(256) void s1_kv_mfma(
    const int* __restrict__ tok, const float* __restrict__ emb,
    const float* __restrict__ Win, const float* __restrict__ b_in,
    unsigned short* __restrict__ khb, unsigned short* __restrict__ vhb)
{
    __shared__ alignas(16) unsigned short SM[17408];   // Al(8192) + Bl(8192); epi: [128][136]
    unsigned short* Al = SM;
    unsigned short* Bl = SM + 8192;
    const int tid = threadIdx.x;
    const int cb = blockIdx.x >> 7;
    const int rb = blockIdx.x & 127;
    const int r0 = rb * 128, c0 = cb * 128;
    int tokrow[8];
#pragma unroll
    for (int j = 0; j < 8; ++j) tokrow[j] = tok[r0 + ((tid + 256 * j) >> 4)];

    const int wid = tid >> 6, lane = tid & 63;
    const int wm = (wid >> 1) * 64, wn = (wid & 1) * 64;
    const int fr = lane & 15;
    const int fkb = (lane >> 4) * 16;
    f32x4 acc[4][4];
#pragma unroll
    for (int i = 0; i < 4; ++i)
#pragma unroll
        for (int j = 0; j < 4; ++j)
#pragma unroll
            for (int e = 0; e < 4; ++e) acc[i][j][e] = 0.0f;

    for (int kt = 0; kt < 512; kt += 64) {
        float4 av[8], bv[8];
#pragma unroll
        for (int j = 0; j < 8; ++j) {
            const int flat = tid + 256 * j;
            const int row = flat >> 4, kq4 = flat & 15;
            av[j] = *(const float4*)(emb + (size_t)tokrow[j] * 512 + kt + kq4 * 4);
            bv[j] = *(const float4*)(Win + (size_t)(512 + c0 + row) * 512 + kt + kq4 * 4);
        }
        __syncthreads();
#pragma unroll
        for (int j = 0; j < 8; ++j) {
            const int flat = tid + 256 * j;
            const int row = flat >> 4, kq4 = flat & 15;
            const int boff = row * 128 + kq4 * 8;
            uint2 pa = { bf2(av[j].x, av[j].y), bf2(av[j].z, av[j].w) };
            uint2 pb = { bf2(bv[j].x, bv[j].y), bf2(bv[j].z, bv[j].w) };
            *(uint2*)((char*)Al + SWZ(boff)) = pa;
            *(uint2*)((char*)Bl + SWZ(boff)) = pb;
        }
        __syncthreads();
#pragma unroll
        for (int ks = 0; ks < 2; ++ks) {
            short8v af[4], bfv[4];
#pragma unroll
            for (int i = 0; i < 4; ++i)
                af[i] = *(const short8v*)((const char*)Al + SWZ((wm + i * 16 + fr) * 128 + ks * 64 + fkb));
#pragma unroll
            for (int j = 0; j < 4; ++j)
                bfv[j] = *(const short8v*)((const char*)Bl + SWZ((wn + j * 16 + fr) * 128 + ks * 64 + fkb));
#pragma unroll
            for (int i = 0; i < 4; ++i)
#pragma unroll
                for (int j = 0; j < 4; ++j)
                    acc[i][j] = __builtin_amdgcn_mfma_f32_16x16x32_bf16(af[i], bfv[j], acc[i][j], 0, 0, 0);
        }
    }
    __syncthreads();
#pragma unroll
    for (int j = 0; j < 4; ++j) {
        const int n = wn + j * 16 + fr;
        const float bias = b_in[512 + c0 + n];
#pragma unroll
        for (int i = 0; i < 4; ++i) {
            const int rbase = wm + i * 16 + (lane >> 4) * 4;
#pragma unroll
            for (int rr = 0; rr < 4; ++rr)
                SM[(rbase + rr) * 136 + n] = bfr(acc[i][j][rr] + bias);
        }
    }
    __syncthreads();
    unsigned short* outbase = (c0 < 512) ? khb : vhb;
    const int ccol = (c0 < 512) ? c0 : (c0 - 512);
    {
        const int orow = tid >> 1, oh = tid & 1;
        unsigned short* gdst = outbase + (size_t)(r0 + orow) * 512 + ccol + oh * 64;
        const unsigned short* lsrc = SM + orow * 136 + oh * 64;
#pragma unroll
        for (int q = 0; q < 8; ++q)
            *(uint4*)(gdst + q * 8) = *(const uint4*)(lsrc + q * 8);
    }
}

// ---------------------------------------------------------------------------
// SETUP2 (after s1): [0,32) s6w: WMt + kmc; [32,544) s6c: khc
// ---------------------------------------------------------------------------
__global__ __launch_bounds__(256) void setup2(
    const float* __restrict__ Win, const float* __restrict__ b_in,
    const unsigned short* __restrict__ Mb, const float* __restrict__ qc0,
    const unsigned short* __restrict__ khb,
    unsigned short* __restrict__ WMt, float* __restrict__ kmc,
    float* __restrict__ khc)
{
    const int tid = threadIdx.x;
    const int bid = blockIdx.x;
    if (bid < 32) {
        __shared__ float Ws[64 * 128];
        __shared__ float Mf[64 * 33];
        __shared__ float bp[64];
        const int h = bid >> 2, ct = bid & 3;
#pragma unroll
        for (int i = 0; i < 8; ++i) {
            const int flat4 = tid + 256 * i;
            const int d = flat4 >> 5, cl4 = flat4 & 31;
            *(float4*)&Ws[d * 128 + cl4 * 4] =
                *(const float4*)(Win + (size_t)(512 + h * 64 + d) * 512 + ct * 128 + cl4 * 4);
        }
#pragma unroll
        for (int i = 0; i < 8; ++i) {
            const int flat = tid + 256 * i;
            const int d = flat >> 5, j2 = flat & 31;
            Mf[d * 33 + j2] = bff(Mb[(size_t)(h * 64 + d) * 32 + j2]);
        }
        if (tid < 64) bp[tid] = b_in[512 + h * 64 + tid];
        __syncthreads();
        const int j = tid & 31, clg = tid >> 5;
        float accw[16];
#pragma unroll
        for (int i = 0; i < 16; ++i) accw[i] = 0.0f;
        for (int d = 0; d < 64; ++d) {
            const float mf = Mf[d * 33 + j];
            const float* wr = &Ws[d * 128 + clg * 16];
#pragma unroll
            for (int i = 0; i < 16; ++i) accw[i] = fmaf(wr[i], mf, accw[i]);
        }
#pragma unroll
        for (int i = 0; i < 16; ++i)
            WMt[(size_t)(h * 32 + j) * 512 + ct * 128 + clg * 16 + i] = bfr(accw[i]);
        if (ct == 0 && clg == 0) {
            float s = 0.0f;
            for (int d = 0; d < 64; ++d) s = fmaf(bp[d], Mf[d * 33 + j], s);
            kmc[h * 32 + j] = s;
        }
    } else {
        __shared__ float qls[512];
        const int sb = bid - 32;
        qls[tid] = qc0[tid];
        qls[tid + 256] = qc0[tid + 256];
        __syncthreads();
        const int h = tid & 7, rl = tid >> 3;
        const int r = sb * 32 + rl;
        const unsigned short* kr = khb + (size_t)r * 512 + h * 64;
        const float* q8 = &qls[h * 64];
        float kc = 0.0f;
#pragma unroll
        for (int i = 0; i < 8; ++i) {
            const uint4 kv = *(const uint4*)(kr + i * 8);
            kc = fmaf(BLO(kv.x), q8[i*8+0], kc); kc = fmaf(BHI(kv.x), q8[i*8+1], kc);
            kc = fmaf(BLO(kv.y), q8[i*8+2], kc); kc = fmaf(BHI(kv.y), q8[i*8+3], kc);
            kc = fmaf(BLO(kv.z), q8[i*8+4], kc); kc = fmaf(BHI(kv.z), q8[i*8+5], kc);
            kc = fmaf(BLO(kv.w), q8[i*8+6], kc); kc = fmaf(BHI(kv.w), q8[i*8+7], kc);
        }
        khc[((size_t)(r >> 9) * 8 + h) * 512 + (r & 511)] = kc;
    }
}

// ---------------------------------------------------------------------------
// S7: MFMA bf16 GEMM: khM(16384 x 256) = gather(emb,tok) @ WMt^T + kmc
// ---------------------------------------------------------------------------
__global__ __launch_bounds__(256) void s7_khm_mfma(
    const int* __restrict__ tok, const float* __restrict__ emb,
    const unsigned short* __restrict__ WMt, const float* __restrict__ kmc,
    unsigned short* __restrict__ khM)
{
    __shared__ alignas(16) unsigned short Al[128 * 64];
    __shared__ alignas(16) unsigned short Bl[128 * 64];
    const int tid = threadIdx.x;
    const int cb = blockIdx.x >> 7;
    const int rb = blockIdx.x & 127;
    const int r0 = rb * 128, c0 = cb * 128;
    int tokrow[8];
#pragma unroll
    for (int j = 0; j < 8; ++j) tokrow[j] = tok[r0 + ((tid + 256 * j) >> 4)];

    const int wid = tid >> 6, lane = tid & 63;
    const int wm = (wid >> 1) * 64, wn = (wid & 1) * 64;
    const int fr = lane & 15;
    const int fkb = (lane >> 4) * 16;
    f32x4 acc[4][4];
#pragma unroll
    for (int i = 0; i < 4; ++i)
#pragma unroll
        for (int j = 0; j < 4; ++j)
#pragma unroll
            for (int e = 0; e < 4; ++e) acc[i][j][e] = 0.0f;

    for (int kt = 0; kt < 512; kt += 64) {
        float4 av[8];
        uint4 bv4[4];
#pragma unroll
        for (int j = 0; j < 8; ++j) {
            const int flat = tid + 256 * j;
            const int row = flat >> 4, kq4 = flat & 15;
            av[j] = *(const float4*)(emb + (size_t)tokrow[j] * 512 + kt + kq4 * 4);
        }
#pragma unroll
        for (int j = 0; j < 4; ++j) {
            const int flat = tid + 256 * j;
            const int row = flat >> 3, kq8 = flat & 7;
            bv4[j] = *(const uint4*)(WMt + (size_t)(c0 + row) * 512 + kt + kq8 * 8);
        }
        __syncthreads();
#pragma unroll
        for (int j = 0; j < 8; ++j) {
            const int flat = tid + 256 * j;
            const int row = flat >> 4, kq4 = flat & 15;
            const int boff = row * 128 + kq4 * 8;
            uint2 pa = { bf2(av[j].x, av[j].y), bf2(av[j].z, av[j].w) };
            *(uint2*)((char*)Al + SWZ(boff)) = pa;
        }
#pragma unroll
        for (int j = 0; j < 4; ++j) {
            const int flat = tid + 256 * j;
            const int row = flat >> 3, kq8 = flat & 7;
            const int boff = row * 128 + kq8 * 16;
            *(uint4*)((char*)Bl + SWZ(boff)) = bv4[j];
        }
        __syncthreads();
#pragma unroll
        for (int ks = 0; ks < 2; ++ks) {
            short8v af[4], bfv[4];
#pragma unroll
            for (int i = 0; i < 4; ++i)
                af[i] = *(const short8v*)((const char*)Al + SWZ((wm + i * 16 + fr) * 128 + ks * 64 + fkb));
#pragma unroll
            for (int j = 0; j < 4; ++j)
                bfv[j] = *(const short8v*)((const char*)Bl + SWZ((wn + j * 16 + fr) * 128 + ks * 64 + fkb));
#pragma unroll
            for (int i = 0; i < 4; ++i)
#pragma unroll
                for (int j = 0; j < 4; ++j)
                    acc[i][j] = __builtin_amdgcn_mfma_f32_16x16x32_bf16(af[i], bfv[j], acc[i][j], 0, 0, 0);
        }
    }
#pragma unroll
    for (int j = 0; j < 4; ++j) {
        const int n = wn + j * 16 + fr;
        const int gc = c0 + n;
        const int h = gc >> 5, jj = gc & 31;
        const float kadd = kmc[gc];
#pragma unroll
        for (int i = 0; i < 4; ++i) {
            const int rbase = wm + i * 16 + (lane >> 4) * 4;
#pragma unroll
            for (int rr = 0; rr < 4; ++rr) {
                const int gr = r0 + rbase + rr;
                khM[(((size_t)(gr >> 9) * 8 + h) * 512 + (gr & 511)) * 32 + jj] =
                    bfr(acc[i][j][rr] + kadd);
            }
        }
    }
}

// ---------------------------------------------------------------------------
// K1: per (b,h), 512 thr: EMA; score = 0.125*(khM.sync + khc); shfl softmax;
// PV from preloaded vh regs -> Ab bf16
// ---------------------------------------------------------------------------
__global__ __launch_bounds__(512) void k1_attn(
    const float* __restrict__ act, const float* __restrict__ decay_a,
    const float* __restrict__ decay_o, const int* __restrict__ ial,
    const int* __restrict__ iar, const int* __restrict__ iol,
    const int* __restrict__ ior,
    const unsigned short* __restrict__ khM, const float* __restrict__ khc,
    const unsigned short* __restrict__ vhb, float* __restrict__ aaB,
    float* __restrict__ baB, float* __restrict__ aoB, float* __restrict__ boB,
    unsigned short* __restrict__ Ab, float* __restrict__ stats, const int u)
{
    __shared__ float sync_lds[32];
    __shared__ float sc[512];
    __shared__ float red[16];
    __shared__ float pvred[512];
    const int tid = threadIdx.x;
    const int b = blockIdx.x >> 3, h = blockIdx.x & 7;

    const size_t mb = (((size_t)b * 8 + h) * 512 + tid) * 32;
    const uint4 km0 = *(const uint4*)(khM + mb);
    const uint4 km1 = *(const uint4*)(khM + mb + 8);
    const uint4 km2 = *(const uint4*)(khM + mb + 16);
    const uint4 km3 = *(const uint4*)(khM + mb + 24);
    const float kc = khc[((size_t)b * 8 + h) * 512 + tid];
    const int l = tid & 63, w = tid >> 6;
    const unsigned short* vb = vhb + ((size_t)(b * 512 + w * 64)) * 512 + h * 64 + l;
    unsigned short vraw[64];
#pragma unroll
    for (int si = 0; si < 64; ++si) vraw[si] = vb[(size_t)si * 512];

    if (tid < 32) {
        const int j = tid;
        const float ra = decf(decay_a[j]);
        const float pa = act[b*2048 + ial[j]] * act[b*2048 + iar[j]];
        const float aa = fmaf(ra, aaB[(u & 1)*1024 + b*32 + j], pa);
        const float ban = fmaf(ra, baB[(u & 1)*1024 + b*32 + j], 1.0f);
        if (h == 0) { aaB[((u+1)&1)*1024 + b*32 + j] = aa; baB[((u+1)&1)*1024 + b*32 + j] = ban; }
        sync_lds[j] = aa * rsqrtf(ban);
    } else if (tid >= 64 && tid < 128) {
        if (u > 0) {
            const int j = tid - 64;
            const float ro = decf(decay_o[j]);
            const float po = act[b*2048 + iol[j]] * act[b*2048 + ior[j]];
            const float ao = fmaf(ro, aoB[((u-1)&1)*2048 + b*64 + j], po);
            const float bo = fmaf(ro, boB[((u-1)&1)*2048 + b*64 + j], 1.0f);
            if (h == 0) { aoB[(u&1)*2048 + b*64 + j] = ao; boB[(u&1)*2048 + b*64 + j] = bo; }
        }
    } else if (tid >= 128 && tid < 192) {
        if (u > 0 && blockIdx.x == 0) stats[tid - 128] = 0.0f;
    }
    __syncthreads();
    float sv = kc;
    {
        const float* sy = sync_lds;
        sv = fmaf(BLO(km0.x), sy[0], sv);  sv = fmaf(BHI(km0.x), sy[1], sv);
        sv = fmaf(BLO(km0.y), sy[2], sv);  sv = fmaf(BHI(km0.y), sy[3], sv);
        sv = fmaf(BLO(km0.z), sy[4], sv);  sv = fmaf(BHI(km0.z), sy[5], sv);
        sv = fmaf(BLO(km0.w), sy[6], sv);  sv = fmaf(BHI(km0.w), sy[7], sv);
        sv = fmaf(BLO(km1.x), sy[8], sv);  sv = fmaf(BHI(km1.x), sy[9], sv);
        sv = fmaf(BLO(km1.y), sy[10], sv); sv = fmaf(BHI(km1.y), sy[11], sv);
        sv = fmaf(BLO(km1.z), sy[12], sv); sv = fmaf(BHI(km1.z), sy[13], sv);
        sv = fmaf(BLO(km1.w), sy[14], sv); sv = fmaf(BHI(km1.w), sy[15], sv);
        sv = fmaf(BLO(km2.x), sy[16], sv); sv = fmaf(BHI(km2.x), sy[17], sv);
        sv = fmaf(BLO(km2.y), sy[18], sv); sv = fmaf(BHI(km2.y), sy[19], sv);
        sv = fmaf(BLO(km2.z), sy[20], sv); sv = fmaf(BHI(km2.z), sy[21], sv);
        sv = fmaf(BLO(km2.w), sy[22], sv); sv = fmaf(BHI(km2.w), sy[23], sv);
        sv = fmaf(BLO(km3.x), sy[24], sv); sv = fmaf(BHI(km3.x), sy[25], sv);
        sv = fmaf(BLO(km3.y), sy[26], sv); sv = fmaf(BHI(km3.y), sy[27], sv);
        sv = fmaf(BLO(km3.z), sy[28], sv); sv = fmaf(BHI(km3.z), sy[29], sv);
        sv = fmaf(BLO(km3.w), sy[30], sv); sv = fmaf(BHI(km3.w), sy[31], sv);
    }
    const float v = sv * 0.125f;
    const int wid = tid >> 6;
    float m = v;
#pragma unroll
    for (int off = 32; off > 0; off >>= 1) m = fmaxf(m, __shfl_xor(m, off));
    if ((tid & 63) == 0) red[wid] = m;
    __syncthreads();
    float mx = red[0];
#pragma unroll
    for (int j = 1; j < 8; ++j) mx = fmaxf(mx, red[j]);
    const float e = __expf(v - mx);
    sc[tid] = e;
    float s = e;
#pragma unroll
    for (int off = 32; off > 0; off >>= 1) s += __shfl_xor(s, off);
    if ((tid & 63) == 0) red[8 + wid] = s;
    __syncthreads();
    float tot = red[8];
#pragma unroll
    for (int j = 1; j < 8; ++j) tot += red[8 + j];
    const float inv = 1.0f / tot;
    {
        float a3 = 0.0f;
#pragma unroll
        for (int si = 0; si < 64; ++si)
            a3 = fmaf(sc[w*64 + si], bff(vraw[si]), a3);
        pvred[w*64 + l] = a3;
    }
    __syncthreads();
    if (tid < 64) {
        float a = 0.0f;
#pragma unroll
        for (int j = 0; j < 8; ++j) a += pvred[j*64 + tid];
        Ab[b*2560 + h*64 + tid] = bfr(a * inv);
    }
}

// ---------------------------------------------------------------------------
// K2b: synapse via MFMA (Wallt: fully-coalesced 1KB wave loads) -> GLU -> sg;
// LN stats atomics
// ---------------------------------------------------------------------------
__global__ __launch_bounds__(512) void k2b_syn(
    const unsigned short* __restrict__ Ab, const unsigned short* __restrict__ Wallt,
    const float* __restrict__ bsyn2, float* __restrict__ sg, float* __restrict__ stats)
{
    __shared__ float part[8 * 512];
    const int tid = threadIdx.x;
    const int c0 = blockIdx.x * 8;
    const int w = tid >> 6, lane = tid & 63, fr = lane & 15, kq = lane >> 4;
    const unsigned short* wrow = Wallt +
        (((size_t)blockIdx.x * 320 + w * 40 + kq) * 16 + fr) * 8;
    const unsigned short* ar0 = Ab + (size_t)fr * 2560 + w*320 + kq*8;
    const unsigned short* ar1 = Ab + (size_t)(16 + fr) * 2560 + w*320 + kq*8;
    f32x4 acc0 = {0.f,0.f,0.f,0.f}, acc1 = {0.f,0.f,0.f,0.f};
#pragma unroll
    for (int kk = 0; kk < 10; ++kk) {
        const short8v bfrag = *(const short8v*)(wrow + kk*512);   // kb += 4 -> 4*16*8
        const short8v a0f = *(const short8v*)(ar0 + kk*32);
        const short8v a1f = *(const short8v*)(ar1 + kk*32);
        acc0 = __builtin_amdgcn_mfma_f32_16x16x32_bf16(a0f, bfrag, acc0, 0, 0, 0);
        acc1 = __builtin_amdgcn_mfma_f32_16x16x32_bf16(a1f, bfrag, acc1, 0, 0, 0);
    }
#pragma unroll
    for (int r = 0; r < 4; ++r) {
        part[w*512 + (kq*4 + r)*16 + fr] = acc0[r];
        part[w*512 + 256 + (kq*4 + r)*16 + fr] = acc1[r];
    }
    __syncthreads();
    float rs = 0.0f;
#pragma unroll
    for (int w2 = 0; w2 < 8; ++w2) rs += part[w2*512 + tid];
    const float other = __shfl_xor(rs, 8);
    const int coli = tid & 15;
    const int m = ((tid >> 8) << 4) | ((tid >> 4) & 15);
    float gval = 0.0f;
    if (coli < 8) {
        const int c = c0 + coli;
        const float va = rs + bsyn2[c];
        const float vg = other + bsyn2[2048 + c];
        gval = va * sigf(vg);
        sg[m*2048 + c] = gval;
    }
    float s1 = gval, s2v = gval*gval;
    s1 += __shfl_xor(s1, 1); s2v += __shfl_xor(s2v, 1);
    s1 += __shfl_xor(s1, 2); s2v += __shfl_xor(s2v, 2);
    s1 += __shfl_xor(s1, 4); s2v += __shfl_xor(s2v, 4);
    if (coli == 0) {
        atomicAdd(&stats[m*2],     s1);
        atomicAdd(&stats[m*2 + 1], s2v);
    }
}

// ---------------------------------------------------------------------------
// K3: LN + trace + per-neuron NLM -> act (+Ab). grid 1024 (2 neurons), 256 thr
// ---------------------------------------------------------------------------
__global__ __launch_bounds__(256) void k3_nlm(
    const float* __restrict__ sg, const float* __restrict__ stats,
    const float* __restrict__ ln_g, const float* __restrict__ ln_b,
    const unsigned short* __restrict__ W1t, const unsigned short* __restrict__ W2t,
    const float* __restrict__ b2,
    float* __restrict__ trace, float* __restrict__ act,
    unsigned short* __restrict__ Ab, const int u)
{
    __shared__ float tr[64 * 12];
    __shared__ float pk[64 * 133];
    const int tid = threadIdx.x;
    const int n0 = blockIdx.x * 2;
    if (tid < 64) {
        const int bb = tid >> 1, nl0 = tid & 1;
        const int n = n0 + nl0;
        float* trow = &tr[tid * 12];
#pragma unroll
        for (int m = 0; m < 9; ++m) {
            const int slot = (u + 1 + m) % 10;
            trow[m] = trace[(bb*10 + slot)*2048 + n];
        }
        const float mean = stats[bb*2] * (1.0f/2048.0f);
        const float var  = stats[bb*2+1] * (1.0f/2048.0f) - mean*mean;
        const float rstd = rsqrtf(var + 1e-5f);
        const float v9 = (sg[bb*2048 + n] - mean) * rstd * ln_g[n] + ln_b[n];
        trow[9] = v9;
        trace[(bb*10 + (u % 10))*2048 + n] = v9;
    }
    const int nl = tid & 1, hg = (tid >> 1) & 63, bh = tid >> 7;
    float w1a[10], w1g[10], b1a, b1g, w2v0, w2v1;
    {
        const unsigned short* pa = W1t + (((size_t)blockIdx.x*128 + hg)*2 + nl)*16;
        const uint4 qa = *(const uint4*)pa;
        const uint4 qb = *(const uint4*)(pa + 8);
        w1a[0] = BLO(qa.x); w1a[1] = BHI(qa.x); w1a[2] = BLO(qa.y); w1a[3] = BHI(qa.y);
        w1a[4] = BLO(qa.z); w1a[5] = BHI(qa.z); w1a[6] = BLO(qa.w); w1a[7] = BHI(qa.w);
        w1a[8] = BLO(qb.x); w1a[9] = BHI(qb.x); b1a = BLO(qb.y);
        const unsigned short* pg = W1t + (((size_t)blockIdx.x*128 + 64 + hg)*2 + nl)*16;
        const uint4 ra = *(const uint4*)pg;
        const uint4 rb = *(const uint4*)(pg + 8);
        w1g[0] = BLO(ra.x); w1g[1] = BHI(ra.x); w1g[2] = BLO(ra.y); w1g[3] = BHI(ra.y);
        w1g[4] = BLO(ra.z); w1g[5] = BHI(ra.z); w1g[6] = BLO(ra.w); w1g[7] = BHI(ra.w);
        w1g[8] = BLO(rb.x); w1g[9] = BHI(rb.x); b1g = BLO(rb.y);
        const unsigned int q2 = *(const unsigned int*)(W2t + (((size_t)blockIdx.x*64 + hg)*2 + nl)*2);
        w2v0 = BLO(q2); w2v1 = BHI(q2);
    }
    __syncthreads();
#pragma unroll
    for (int bi = 0; bi < 16; ++bi) {
        const int bb = bh * 16 + bi;
        const float* trow = &tr[(bb*2 + nl)*12];
        const float4 t0 = *(const float4*)trow;
        const float4 t1 = *(const float4*)(trow + 4);
        const float2 t2 = *(const float2*)(trow + 8);
        const float t[10] = {t0.x,t0.y,t0.z,t0.w,t1.x,t1.y,t1.z,t1.w,t2.x,t2.y};
        float ha = b1a, hgv = b1g;
#pragma unroll
        for (int mm = 0; mm < 10; ++mm) {
            ha  = fmaf(t[mm], w1a[mm], ha);
            hgv = fmaf(t[mm], w1g[mm], hgv);
        }
        const float g0 = ha * sigf(hgv);
        pk[hg*133 + bb*4 + nl*2 + 0] = g0 * w2v0;
        pk[hg*133 + bb*4 + nl*2 + 1] = g0 * w2v1;
    }
    __syncthreads();
    if (tid < 128) {
        const int obb = tid >> 2, onl = (tid >> 1) & 1, oo = tid & 1;
        float rs = 0.0f;
#pragma unroll 8
        for (int q = 0; q < 64; ++q) rs += pk[q*133 + tid];
        rs += b2[(n0 + onl)*2 + oo];
        const float h2o = __shfl_xor(rs, 1);
        if (oo == 0) {
            const float actv = rs * sigf(h2o);
            act[obb*2048 + n0 + onl] = actv;
            Ab[obb*2560 + 512 + n0 + onl] = bfr(actv);
        }
    }
}

// ---------------------------------------------------------------------------
// K4: final o-update, sync_o, ratings, cert
// ---------------------------------------------------------------------------
__global__ __launch_bounds__(256) void k4_final(
    const float* __restrict__ aoB, const float* __restrict__ boB,
    const float* __restrict__ act, const float* __restrict__ decay_o,
    const int* __restrict__ iol, const int* __restrict__ ior,
    const float* __restrict__ Wout, const float* __restrict__ bout,
    float* __restrict__ out)
{
    __shared__ float sl[2048];
    const int tid = threadIdx.x;
    for (int idx = tid; idx < 2048; idx += 256) {
        const int b = idx >> 6, j = idx & 63;
        const float ro = decf(decay_o[j]);
        const float po = act[b*2048 + iol[j]] * act[b*2048 + ior[j]];
        const float ao = fmaf(ro, aoB[2048 + b*64 + j], po);
        const float bo = fmaf(ro, boB[2048 + b*64 + j], 1.0f);
        const float sv = ao * rsqrtf(bo);
        sl[idx] = sv;
        out[96 + idx] = sv;
    }
    __syncthreads();
    if (tid < 32) {
        float p = bout[0];
        for (int j = 0; j < 64; ++j) p = fmaf(sl[tid*64 + j], Wout[j], p);
        out[tid] = sigf(p);
    } else if (tid < 96) {
        out[32 + (tid - 32)] = ((tid - 32) & 1) ? 1.0f : 0.0f;
    }
}

// ---------------------------------------------------------------------------
extern "C" void kernel_launch(void* const* d_in, const int* in_sizes, int n_in,
                              void* d_out, int out_size, void* d_ws, size_t ws_size,
                              hipStream_t stream)
{
    (void)in_sizes; (void)n_in; (void)out_size;
    const int*   tok   = (const int*)  d_in[0];
    const float* emb   = (const float*)d_in[1];
    const float* st_tr = (const float*)d_in[2];
    const float* st_ac = (const float*)d_in[3];
    const float* dec_a = (const float*)d_in[4];
    const float* dec_o = (const float*)d_in[5];
    const int*   ial   = (const int*)  d_in[6];
    const int*   iar   = (const int*)  d_in[7];
    const int*   iol   = (const int*)  d_in[8];
    const int*   ior   = (const int*)  d_in[9];
    const float* Wq    = (const float*)d_in[10];
    const float* bq    = (const float*)d_in[11];
    const float* Win   = (const float*)d_in[12];
    const float* b_in  = (const float*)d_in[13];
    const float* Wao   = (const float*)d_in[14];
    const float* bao   = (const float*)d_in[15];
    const float* Wsyn  = (const float*)d_in[16];
    const float* bsyn  = (const float*)d_in[17];
    const float* ln_g  = (const float*)d_in[18];
    const float* ln_b  = (const float*)d_in[19];
    const float* W1    = (const float*)d_in[20];
    const float* b1    = (const float*)d_in[21];
    const float* W2    = (const float*)d_in[22];
    const float* b2    = (const float*)d_in[23];
    const float* Wout  = (const float*)d_in[24];
    const float* bout  = (const float*)d_in[25];
    float* out = (float*)d_out;
    char* wsb = (char*)d_ws;
    if (ws_size < (size_t)76025088) return;
    unsigned short* khb   = (unsigned short*)(wsb + 0);          // 16 MB
    unsigned short* vhb   = (unsigned short*)(wsb + 16777216);   // 16 MB
    unsigned short* Wallt = (unsigned short*)(wsb + 33554432);   // 20 MB
    unsigned short* W1t   = (unsigned short*)(wsb + 54525952);   // 8 MB
    unsigned short* W2t   = (unsigned short*)(wsb + 62914560);   // 512 KB
    unsigned short* khM   = (unsigned short*)(wsb + 63438848);   // 8 MB
    float* khc  = (float*)(wsb + 71827456);                      // 512 KB
    unsigned short* Mb    = (unsigned short*)(wsb + 72351744);   // 32 KB
    float* qc0  = (float*)(wsb + 72384512);                      // 2 KB
    float* trace = (float*)(wsb + 72386560);                     // 2.5 MB
    float* actb  = (float*)(wsb + 75008000);                     // 256 KB
    float* sg    = (float*)(wsb + 75270144);                     // 256 KB
    unsigned short* Ab = (unsigned short*)(wsb + 75532288);      // 160 KB
    float* aaB   = (float*)(wsb + 75696128);
    float* baB   = (float*)(wsb + 75704320);
    float* aoB   = (float*)(wsb + 75712512);
    float* boB   = (float*)(wsb + 75728896);
    float* bs2   = (float*)(wsb + 75745280);
    float* stats = (float*)(wsb + 75761664);
    unsigned short* WMt = (unsigned short*)(wsb + 75761920);     // 256 KB
    float* kmc  = (float*)(wsb + 76024064);                      // 1 KB

    setup1<<<dim3(12137), dim3(256), 0, stream>>>(
        st_tr, st_ac, iol, ior, trace, actb, Ab, aaB, baB, aoB, boB, stats,
        Wsyn, Wallt, bao, bsyn, bs2, W1, b1, W2, W1t, W2t,
        Win, b_in, Wq, bq, Mb, qc0);
    s2_wfused<<<dim3(512), dim3(256), 0, stream>>>(Wsyn, Wao, Wallt);
    s1_kv_mfma<<<dim3(1024), dim3(256), 0, stream>>>(tok, emb, Win, b_in, khb, vhb);
    setup2<<<dim3(544), dim3(256), 0, stream>>>(Win, b_in, Mb, qc0, khb, WMt, kmc, khc);
    s7_khm_mfma<<<dim3(256), dim3(256), 0, stream>>>(tok, emb, WMt, kmc, khM);
    for (int u = 0; u < 20; ++u) {
        k1_attn<<<dim3(256), dim3(512), 0, stream>>>(actb, dec_a, dec_o,
            ial, iar, iol, ior, khM, khc, vhb,
            aaB, baB, aoB, boB, Ab, stats, u);
        k2b_syn<<<dim3(256), dim3(512), 0, stream>>>(Ab, Wallt, bs2, sg, stats);
        k3_nlm<<<dim3(1024), dim3(256), 0, stream>>>(sg, stats, ln_g, ln_b,
            W1t, W2t, b2, trace, actb, Ab, u);
    }
    k4_final<<<dim3(1), dim3(256), 0, stream>>>(aoB, boB, actb, dec_o,
        iol, ior, Wout, bout, out);
}